// Round 13
// baseline (2347.073 us; speedup 1.0000x reference)
//
#include <hip/hip_runtime.h>
#include <hip/hip_bf16.h>
#include <cstdint>
#include <cstddef>

#define B_ 32
#define T_ 128
#define H_ 1024
#define V_ 32000
#define NBS 192            // staircase blocks (3 layers x 64 groups); +64 FC blocks
#define NITER (T_ + 4)     // lag-2 staircase: layer l at tl = s - 2l
#define FS 32              // flag stride (ints) = 128B per flag line
#define NJOBS2 232         // phase-2: 58 by-columns x 4 chunks of 8 bx

using bf16 = __hip_bfloat16;
typedef __attribute__((ext_vector_type(8))) short short8;
typedef __attribute__((ext_vector_type(4))) float f32x4;

__device__ __forceinline__ float bf2f(unsigned short u) {
    return __uint_as_float(((unsigned)u) << 16);
}

__device__ __forceinline__ void lds_cp16(const void* g, void* l) {
    __builtin_amdgcn_global_load_lds(
        (const __attribute__((address_space(1))) unsigned int*)g,
        (__attribute__((address_space(3))) unsigned int*)l, 16, 0, 0);
}

__device__ __forceinline__ unsigned long long coh_load8(const unsigned long long* p) {
    return __hip_atomic_load(p, __ATOMIC_RELAXED, __HIP_MEMORY_SCOPE_AGENT);
}

// ---------------------------------------------------------------------------
// merged f32->bf16 conversion of the 6 GRU weight matrices
__global__ __launch_bounds__(256)
void convW_kernel(const float* __restrict__ s0, bf16* __restrict__ d0,
                  const float* __restrict__ s1, bf16* __restrict__ d1,
                  const float* __restrict__ s2, bf16* __restrict__ d2,
                  const float* __restrict__ s3, bf16* __restrict__ d3,
                  const float* __restrict__ s4, bf16* __restrict__ d4,
                  const float* __restrict__ s5, bf16* __restrict__ d5) {
    const int bid = blockIdx.x;
    const float* src; bf16* dst; int i8;
    if (bid < 3072) { src = s0; dst = d0; i8 = bid * 256 + threadIdx.x; }
    else {
        int r = (bid - 3072) / 1536;
        int rb = (bid - 3072) % 1536;
        i8 = rb * 256 + threadIdx.x;
        switch (r) {
            case 0: src = s1; dst = d1; break;
            case 1: src = s2; dst = d2; break;
            case 2: src = s3; dst = d3; break;
            case 3: src = s4; dst = d4; break;
            default: src = s5; dst = d5; break;
        }
    }
    const float4* s = (const float4*)(src + (size_t)i8 * 8);
    float4 a = s[0], b = s[1];
    ushort4 o0, o1;
    o0.x = __bfloat16_as_ushort(__float2bfloat16(a.x));
    o0.y = __bfloat16_as_ushort(__float2bfloat16(a.y));
    o0.z = __bfloat16_as_ushort(__float2bfloat16(a.z));
    o0.w = __bfloat16_as_ushort(__float2bfloat16(a.w));
    o1.x = __bfloat16_as_ushort(__float2bfloat16(b.x));
    o1.y = __bfloat16_as_ushort(__float2bfloat16(b.y));
    o1.z = __bfloat16_as_ushort(__float2bfloat16(b.z));
    o1.w = __bfloat16_as_ushort(__float2bfloat16(b.w));
    ((ushort4*)(dst + (size_t)i8 * 8))[0] = o0;
    ((ushort4*)(dst + (size_t)i8 * 8))[1] = o1;
}

// ---------------------------------------------------------------------------
// embed: X[t*B+b] = [bf16(word_emb[token]) | bf16(cat_emb[cat])]
__global__ __launch_bounds__(256)
void embed_kernel(const int* __restrict__ tok, const int* __restrict__ cat,
                  const float* __restrict__ wemb, const float* __restrict__ cemb,
                  bf16* __restrict__ X) {
    const int tb = blockIdx.x;
    const int t = tb >> 5, b = tb & 31;
    const int token = tok[b * T_ + t];
    const int c = cat[b * T_ + t];
    const int i = threadIdx.x;
    const float* src = (i < 128) ? (wemb + (size_t)token * H_ + (size_t)i * 8)
                                 : (cemb + (size_t)c * H_ + (size_t)(i - 128) * 8);
    float4 a = ((const float4*)src)[0];
    float4 bv = ((const float4*)src)[1];
    ushort4 o0, o1;
    o0.x = __bfloat16_as_ushort(__float2bfloat16(a.x));
    o0.y = __bfloat16_as_ushort(__float2bfloat16(a.y));
    o0.z = __bfloat16_as_ushort(__float2bfloat16(a.z));
    o0.w = __bfloat16_as_ushort(__float2bfloat16(a.w));
    o1.x = __bfloat16_as_ushort(__float2bfloat16(bv.x));
    o1.y = __bfloat16_as_ushort(__float2bfloat16(bv.y));
    o1.z = __bfloat16_as_ushort(__float2bfloat16(bv.z));
    o1.w = __bfloat16_as_ushort(__float2bfloat16(bv.w));
    ushort4* d = (ushort4*)(X + (size_t)tb * 2 * H_ + (size_t)i * 8);
    d[0] = o0;
    d[1] = o1;
}

// ---------------------------------------------------------------------------
// MFMA GEMM: C[M,N] = A[M,K] @ Bm[N,K]^T + bias[N] (fp32 row-major out)
__global__ __launch_bounds__(256)
void gemm_bt(const bf16* __restrict__ A, const bf16* __restrict__ Bm,
             const float* __restrict__ bias, float* __restrict__ Cf,
             int M, int N, int K) {
    __shared__ __align__(16) bf16 As[128 * 64];
    __shared__ __align__(16) bf16 Bs[128 * 64];
    const int tid = threadIdx.x;
    const int lane = tid & 63;
    const int wid = tid >> 6;
    const int row0 = blockIdx.x * 128;
    const int col0 = blockIdx.y * 128;
    const int rw0 = (wid >> 1) * 64;
    const int cw0 = (wid & 1) * 64;
    const int lr = lane & 15;
    const int lg = lane >> 4;
    f32x4 acc[4][4] = {};
    const int nk = K >> 6;
    for (int kt = 0; kt < nk; ++kt) {
        const int k0 = kt * 64;
#pragma unroll
        for (int i = 0; i < 4; ++i) {
            int c = i * 256 + tid;
            int r = c >> 3;
            int kc = (c & 7) * 8;
            lds_cp16(A + (size_t)(row0 + r) * K + (k0 + kc), (void*)(As + c * 8));
            lds_cp16(Bm + (size_t)(col0 + r) * K + (k0 + kc), (void*)(Bs + c * 8));
        }
        __syncthreads();
#pragma unroll
        for (int s = 0; s < 2; ++s) {
            short8 af[4], bfr[4];
#pragma unroll
            for (int m = 0; m < 4; ++m)
                af[m] = *(const short8*)(As + (rw0 + m * 16 + lr) * 64 + s * 32 + lg * 8);
#pragma unroll
            for (int n = 0; n < 4; ++n)
                bfr[n] = *(const short8*)(Bs + (cw0 + n * 16 + lr) * 64 + s * 32 + lg * 8);
#pragma unroll
            for (int m = 0; m < 4; ++m)
#pragma unroll
                for (int n = 0; n < 4; ++n)
                    acc[m][n] = __builtin_amdgcn_mfma_f32_16x16x32_bf16(bfr[n], af[m], acc[m][n], 0, 0, 0);
        }
        __syncthreads();
    }
#pragma unroll
    for (int m = 0; m < 4; ++m) {
#pragma unroll
        for (int n = 0; n < 4; ++n) {
            int r = row0 + rw0 + m * 16 + lr;
            int c0b = col0 + cw0 + n * 16 + lg * 4;
            f32x4 v = acc[m][n] + *(const f32x4*)(bias + c0b);
            *(f32x4*)(Cf + (size_t)r * N + c0b) = v;
        }
    }
}

// ---------------------------------------------------------------------------
// stair_init: Hx parity-0 = packed bf16(h_l); zero padded flags + aux
__global__ __launch_bounds__(256)
void stair_init(const float* __restrict__ h1, const float* __restrict__ h2,
                const float* __restrict__ h3, unsigned* __restrict__ Hx,
                int* __restrict__ flags, int* __restrict__ aux) {
    int idx = blockIdx.x * 256 + threadIdx.x;   // < 3*16384
    if (idx < NBS * FS) flags[idx] = 0;
    if (idx < 64 * FS + 64) aux[idx] = 0;       // wq counter + padded fcflags
    int l = idx >> 14, r = idx & 16383;
    int b = r >> 9, k = r & 511;
    const float* h = (l == 0 ? h1 : (l == 1 ? h2 : h3));
    unsigned lo = __bfloat16_as_ushort(__float2bfloat16(h[b * H_ + 2 * k]));
    unsigned hi = __bfloat16_as_ushort(__float2bfloat16(h[b * H_ + 2 * k + 1]));
    Hx[((l * 2 + 0) * 32 + b) * 512 + k] = lo | (hi << 16);
}

// ---------------------------------------------------------------------------
// padded-flag waits: flag i lives at base[i*FS]; one lane per flag, latched
__device__ __forceinline__ void wait_flags(const int* flags, int base, int nflags,
                                           int thr, int own) {
    const int tid = threadIdx.x;
    int mine = 1;
    const int* fp = nullptr;
    int idx = base + tid;
    if (tid < nflags) { fp = flags + (size_t)idx * FS; mine = (idx == own) ? 1 : 0; }
    int done = 0;
    do {
        if (!mine)
            mine = (__hip_atomic_load(fp, __ATOMIC_RELAXED, __HIP_MEMORY_SCOPE_AGENT) >= thr);
        done = __syncthreads_and(mine);
    } while (!done);
}

__device__ __forceinline__ void wait_flags_sleep(const int* flags, int base, int nflags,
                                                 int thr) {
    const int tid = threadIdx.x;
    int mine = 1;
    const int* fp = nullptr;
    if (tid < nflags) { fp = flags + (size_t)(base + tid) * FS; mine = 0; }
    int done = 0;
    do {
        if (!mine)
            mine = (__hip_atomic_load(fp, __ATOMIC_RELAXED, __HIP_MEMORY_SCOPE_AGENT) >= thr);
        done = __syncthreads_and(mine);
        if (!done) __builtin_amdgcn_s_sleep(16);
    } while (!done);
}

// ---------------------------------------------------------------------------
// Fused persistent kernel:
//   blocks 0..191   : lag-2 staircase, then JOIN the phase-2 FC queue
//   blocks 192..255 : fcw conversion prologue (bigws), phase-1 paced FC
//                     (3 static by-columns, bx-outer flag-gated), then phase-2
template<int BF16W>
__global__ __launch_bounds__(256, 1)
void stair_fc(const float* __restrict__ GI0,
              const bf16* __restrict__ Wih2, const bf16* __restrict__ Wih3,
              const bf16* __restrict__ Whh1, const bf16* __restrict__ Whh2,
              const bf16* __restrict__ Whh3,
              const float* __restrict__ bih2, const float* __restrict__ bih3,
              const float* __restrict__ bhh1, const float* __restrict__ bhh2,
              const float* __restrict__ bhh3,
              const float* __restrict__ h1, const float* __restrict__ h2,
              const float* __restrict__ h3,
              unsigned* __restrict__ Hx, int* __restrict__ flags,
              int* __restrict__ aux,
              unsigned* __restrict__ c1, unsigned* __restrict__ c2,
              unsigned* __restrict__ c3, float* __restrict__ outt,
              const float* __restrict__ fcw32, bf16* __restrict__ fcwB,
              const float* __restrict__ fcb, float* __restrict__ outp) {
    __shared__ __align__(16) char smem[127488];
    const int tid = threadIdx.x;
    const int lane = tid & 63;
    const int wid = tid >> 6;
    const int lr = lane & 15;
    const int lg = lane >> 4;

    if (blockIdx.x < NBS) {
        // ================= staircase path (round-10 datapath) =================
        float* PlH = (float*)smem;                    // 24KB
        float* PlI = (float*)(smem + 24576);          // 24KB
        float* RrH = (float*)(smem + 49152);          // 6KB
        float* RrI = (float*)(smem + 55296);          // 6KB
        char* cbuf = smem + 61440;                    // 66048B (32 rows x 2064B)
        const int l = blockIdx.x >> 6;
        const int u0 = (blockIdx.x & 63) * 16;
        const int kbase = wid * 256;

        const bf16* Whh = (l == 0) ? Whh1 : ((l == 1) ? Whh2 : Whh3);
        const bf16* Wih = (l == 1) ? Wih2 : Wih3;
        const float* bhh = (l == 0) ? bhh1 : ((l == 1) ? bhh2 : bhh3);
        const float* bih = (l == 1) ? bih2 : bih3;
        const float* hinit = (l == 0) ? h1 : ((l == 1) ? h2 : h3);
        const unsigned short* wh = (const unsigned short*)Whh;
        const unsigned short* wi = (const unsigned short*)Wih;
        const unsigned* Cin = (l == 1) ? c1 : c2;
        unsigned* Cout = (l == 0) ? c1 : c2;

        const int fbase = (l == 0) ? 0 : 64 * (l - 1);
        const int fn = (l == 0) ? 64 : 128;

        short8 wfH[3][8];
#pragma unroll
        for (int g = 0; g < 3; ++g)
#pragma unroll
            for (int kf = 0; kf < 8; ++kf)
                wfH[g][kf] = *(const short8*)(wh + (size_t)(g * H_ + u0 + lr) * H_ + kbase + kf * 32 + lg * 8);

        const int gb = tid >> 3;
        const int up = tid & 7;
        float hold0 = hinit[(size_t)gb * H_ + u0 + 2 * up];
        float hold1 = hinit[(size_t)gb * H_ + u0 + 2 * up + 1];

        float bhA = bhh[((tid >> 3) >> 4) * H_ + u0 + ((tid >> 3) & 15)];
        float bhB = (tid < 128) ? bhh[(((tid + 256) >> 3) >> 4) * H_ + u0 + (((tid + 256) >> 3) & 15)] : 0.f;
        float biA = 0.f, biB = 0.f;
        if (l > 0) {
            biA = bih[((tid >> 3) >> 4) * H_ + u0 + ((tid >> 3) & 15)];
            if (tid < 128) biB = bih[(((tid + 256) >> 3) >> 4) * H_ + u0 + (((tid + 256) >> 3) & 15)];
        }

        for (int s = 0; s < NITER; ++s) {
            const int tl = s - 2 * l;
            const bool act = (tl >= 0) && (tl < T_);
            const int tln = tl + 1;
            const bool pre = (l > 0) && (tln >= 0) && (tln < T_);
            float g0r = 0.f, g0z = 0.f, g0n = 0.f, g1r = 0.f, g1z = 0.f, g1n = 0.f;
            if (l == 0 && act) {
                const float* gi = GI0 + ((size_t)tl * B_ + gb) * 3072 + u0 + 2 * up;
                g0r = gi[0];    g1r = gi[1];
                g0z = gi[1024]; g1z = gi[1025];
                g0n = gi[2048]; g1n = gi[2049];
            }
            wait_flags(flags, fbase, fn, s, blockIdx.x);

            f32x4 accH[2][3] = {};
            f32x4 accI[2][3] = {};
            unsigned long long harr[32];
            if (act) {
                const unsigned* hsrc = Hx + (size_t)((l * 2 + (tl & 1)) * 32) * 512;
#pragma unroll
                for (int kf = 0; kf < 8; ++kf) {
                    const int co = (kbase >> 1) + kf * 16 + lg * 4;
                    const unsigned long long* p0 = (const unsigned long long*)(hsrc + (size_t)lr * 512 + co);
                    const unsigned long long* p1 = (const unsigned long long*)(hsrc + (size_t)(16 + lr) * 512 + co);
                    harr[kf * 4 + 0] = coh_load8(p0);
                    harr[kf * 4 + 1] = coh_load8(p0 + 1);
                    harr[kf * 4 + 2] = coh_load8(p1);
                    harr[kf * 4 + 3] = coh_load8(p1 + 1);
                }
                if (l > 0) {
#pragma unroll
                    for (int kf = 0; kf < 8; ++kf) {
                        const int kb2 = kbase * 2 + kf * 64 + lg * 16;
                        short8 cv0 = *(const short8*)(cbuf + lr * 2064 + kb2);
                        short8 cv1 = *(const short8*)(cbuf + (16 + lr) * 2064 + kb2);
                        const int ko = kbase + kf * 32 + lg * 8;
#pragma unroll
                        for (int g = 0; g < 3; ++g) {
                            short8 w = *(const short8*)(wi + (size_t)(g * H_ + u0 + lr) * H_ + ko);
                            accI[0][g] = __builtin_amdgcn_mfma_f32_16x16x32_bf16(cv0, w, accI[0][g], 0, 0, 0);
                            accI[1][g] = __builtin_amdgcn_mfma_f32_16x16x32_bf16(cv1, w, accI[1][g], 0, 0, 0);
                        }
                    }
                }
#pragma unroll
                for (int kf = 0; kf < 8; ++kf) {
                    union { unsigned long long u[2]; short8 s8; } a0, a1;
                    a0.u[0] = harr[kf * 4 + 0]; a0.u[1] = harr[kf * 4 + 1];
                    a1.u[0] = harr[kf * 4 + 2]; a1.u[1] = harr[kf * 4 + 3];
#pragma unroll
                    for (int g = 0; g < 3; ++g) {
                        accH[0][g] = __builtin_amdgcn_mfma_f32_16x16x32_bf16(a0.s8, wfH[g][kf], accH[0][g], 0, 0, 0);
                        accH[1][g] = __builtin_amdgcn_mfma_f32_16x16x32_bf16(a1.s8, wfH[g][kf], accH[1][g], 0, 0, 0);
                    }
                }
#pragma unroll
                for (int m = 0; m < 2; ++m)
#pragma unroll
                    for (int g = 0; g < 3; ++g) {
                        int col = g * 16 + lr;
                        int key = (col + (col >> 3)) & 7;
                        int byte_off = wid * 6144 + col * 128 + (((m * 16 + lg * 4) * 4) ^ (key << 4));
                        *(f32x4*)((char*)PlH + byte_off) = accH[m][g];
                        if (l > 0) *(f32x4*)((char*)PlI + byte_off) = accI[m][g];
                    }
            }
            __syncthreads();
            unsigned long long ctmp[32];
            if (pre) {
                const unsigned* csrc = Cin + (size_t)tln * (B_ * 512);
#pragma unroll
                for (int kf = 0; kf < 8; ++kf) {
                    const int co = (kbase >> 1) + kf * 16 + lg * 4;
                    const unsigned long long* p0 = (const unsigned long long*)(csrc + (size_t)lr * 512 + co);
                    const unsigned long long* p1 = (const unsigned long long*)(csrc + (size_t)(16 + lr) * 512 + co);
                    ctmp[kf * 4 + 0] = coh_load8(p0);
                    ctmp[kf * 4 + 1] = coh_load8(p0 + 1);
                    ctmp[kf * 4 + 2] = coh_load8(p1);
                    ctmp[kf * 4 + 3] = coh_load8(p1 + 1);
                }
            }
            if (act) {
#pragma unroll
                for (int it = 0; it < 2; ++it) {
                    int task = tid + it * 256;
                    if (task < 384) {
                        int col = task >> 3, bq = task & 7;
                        int key = (col + (col >> 3)) & 7;
                        int boff = col * 128 + ((bq * 16) ^ (key << 4));
                        float bh = (it == 0) ? bhA : bhB;
                        f32x4 s0 = *(const f32x4*)((const char*)PlH + boff);
                        f32x4 s1 = *(const f32x4*)((const char*)PlH + 6144 + boff);
                        f32x4 s2 = *(const f32x4*)((const char*)PlH + 12288 + boff);
                        f32x4 s3 = *(const f32x4*)((const char*)PlH + 18432 + boff);
                        f32x4 sv = (s0 + s1) + (s2 + s3);
                        sv[0] += bh; sv[1] += bh; sv[2] += bh; sv[3] += bh;
                        *(f32x4*)((char*)RrH + boff) = sv;
                        if (l > 0) {
                            float bi = (it == 0) ? biA : biB;
                            f32x4 t0 = *(const f32x4*)((const char*)PlI + boff);
                            f32x4 t1 = *(const f32x4*)((const char*)PlI + 6144 + boff);
                            f32x4 t2 = *(const f32x4*)((const char*)PlI + 12288 + boff);
                            f32x4 t3 = *(const f32x4*)((const char*)PlI + 18432 + boff);
                            f32x4 tv = (t0 + t1) + (t2 + t3);
                            tv[0] += bi; tv[1] += bi; tv[2] += bi; tv[3] += bi;
                            *(f32x4*)((char*)RrI + boff) = tv;
                        }
                    }
                }
            }
            __syncthreads();
            if (act) {
                float hn[2];
#pragma unroll
                for (int e = 0; e < 2; ++e) {
                    int u = 2 * up + e;
                    int colR = u, colZ = 16 + u, colN = 32 + u;
                    int keyR = (colR + (colR >> 3)) & 7;
                    int keyZ = (colZ + (colZ >> 3)) & 7;
                    int keyN = (colN + (colN >> 3)) & 7;
                    float ghr = *(const float*)((const char*)RrH + colR * 128 + ((gb * 4) ^ (keyR << 4)));
                    float ghz = *(const float*)((const char*)RrH + colZ * 128 + ((gb * 4) ^ (keyZ << 4)));
                    float ghn = *(const float*)((const char*)RrH + colN * 128 + ((gb * 4) ^ (keyN << 4)));
                    float gir, giz, gin;
                    if (l == 0) {
                        gir = (e == 0) ? g0r : g1r;
                        giz = (e == 0) ? g0z : g1z;
                        gin = (e == 0) ? g0n : g1n;
                    } else {
                        gir = *(const float*)((const char*)RrI + colR * 128 + ((gb * 4) ^ (keyR << 4)));
                        giz = *(const float*)((const char*)RrI + colZ * 128 + ((gb * 4) ^ (keyZ << 4)));
                        gin = *(const float*)((const char*)RrI + colN * 128 + ((gb * 4) ^ (keyN << 4)));
                    }
                    float holdv = (e == 0) ? hold0 : hold1;
                    float rr = 1.f / (1.f + expf(-(gir + ghr)));
                    float zz = 1.f / (1.f + expf(-(giz + ghz)));
                    float nn = tanhf(gin + rr * ghn);
                    float hnew = (1.f - zz) * nn + zz * holdv;
                    if (e == 0) hold0 = hnew; else hold1 = hnew;
                    hn[e] = hnew;
                }
                unsigned lo = __bfloat16_as_ushort(__float2bfloat16(hn[0]));
                unsigned hi = __bfloat16_as_ushort(__float2bfloat16(hn[1]));
                unsigned pk = lo | (hi << 16);
                __hip_atomic_store(Hx + (size_t)((l * 2 + ((tl + 1) & 1)) * 32 + gb) * 512 + (u0 >> 1) + up,
                                   pk, __ATOMIC_RELAXED, __HIP_MEMORY_SCOPE_AGENT);
                if (l < 2)
                    __hip_atomic_store(Cout + ((size_t)tl * B_ + gb) * 512 + (u0 >> 1) + up,
                                       pk, __ATOMIC_RELAXED, __HIP_MEMORY_SCOPE_AGENT);
                else
                    __hip_atomic_store(c3 + ((size_t)tl * B_ + gb) * 512 + (u0 >> 1) + up,
                                       pk, __ATOMIC_RELAXED, __HIP_MEMORY_SCOPE_AGENT);
            }
            asm volatile("s_waitcnt vmcnt(0)" ::: "memory");
            __syncthreads();
            if (tid == 0)
                __hip_atomic_store(&flags[(size_t)blockIdx.x * FS], s + 1,
                                   __ATOMIC_RELAXED, __HIP_MEMORY_SCOPE_AGENT);
            if (pre) {
#pragma unroll
                for (int kf = 0; kf < 8; ++kf) {
                    const int kb2 = kbase * 2 + kf * 64 + lg * 16;
                    unsigned long long* d0 = (unsigned long long*)(cbuf + lr * 2064 + kb2);
                    unsigned long long* d1 = (unsigned long long*)(cbuf + (16 + lr) * 2064 + kb2);
                    d0[0] = ctmp[kf * 4 + 0];
                    d0[1] = ctmp[kf * 4 + 1];
                    d1[0] = ctmp[kf * 4 + 2];
                    d1[1] = ctmp[kf * 4 + 3];
                }
            }
        }
        outt[(size_t)l * 32768 + (size_t)(tid >> 3) * H_ + u0 + 2 * (tid & 7)] = hold0;
        outt[(size_t)l * 32768 + (size_t)(tid >> 3) * H_ + u0 + 2 * (tid & 7) + 1] = hold1;
        __syncthreads();
        // fall through: join phase-2 FC queue
    } else {
        // FC prologue: convert this block's 500-row fcw slice to bf16 via LLC stores
        if (BF16W) {
            const int fcid = blockIdx.x - NBS;   // 0..63
            const float2* src = (const float2*)(fcw32 + (size_t)fcid * 500 * 1024);
            unsigned* dst = (unsigned*)fcwB + (size_t)fcid * 500 * 512;
            for (int i = tid; i < 500 * 512; i += 256) {
                float2 v = src[i];
                unsigned pk = (unsigned)__bfloat16_as_ushort(__float2bfloat16(v.x)) |
                              ((unsigned)__bfloat16_as_ushort(__float2bfloat16(v.y)) << 16);
                __hip_atomic_store(dst + i, pk, __ATOMIC_RELAXED, __HIP_MEMORY_SCOPE_AGENT);
            }
            asm volatile("s_waitcnt vmcnt(0)" ::: "memory");
            __syncthreads();
            if (tid == 0)
                __hip_atomic_store(&aux[64 + (blockIdx.x - NBS) * FS], 1,
                                   __ATOMIC_RELAXED, __HIP_MEMORY_SCOPE_AGENT);
            wait_flags_sleep(aux + 64, 0, 64, 1);
        }
    }

    // ===================== shared FC tile machinery =====================
    {
        bf16* As = (bf16*)smem;               // 16KB (swizzled bf16 tiles)
        bf16* Bs16 = (bf16*)(smem + 16384);   // 16KB
        float* Bs32 = (float*)(smem + 16384); // 32KB (f32 mode)
        int* jslot = (int*)(smem + 126976);
        const bf16* Abase = (const bf16*)c3;
        const bf16* fcwBr = (const bf16*)fcwB;
        const int rw0 = (wid >> 1) * 64;
        const int cw0 = (wid & 1) * 64;

        auto fc_tile = [&](int bx, int by) {
            const int row0 = bx * 128, col0 = by * 128;
            f32x4 acc[4][4] = {};
            for (int kt = 0; kt < 16; ++kt) {
                const int k0 = kt * 64;
#pragma unroll
                for (int i = 0; i < 4; ++i) {
                    int c = i * 256 + tid;
                    int r = c >> 3;
                    int sb = ((c & 7) * 16) ^ ((r & 7) << 4);
                    lds_cp16(Abase + (size_t)(row0 + r) * 1024 + k0 + (sb >> 1),
                             (char*)As + c * 16);
                }
                if (BF16W) {
#pragma unroll
                    for (int i = 0; i < 4; ++i) {
                        int c = i * 256 + tid;
                        int r = c >> 3;
                        int sb = ((c & 7) * 16) ^ ((r & 7) << 4);
                        lds_cp16(fcwBr + (size_t)(col0 + r) * 1024 + k0 + (sb >> 1),
                                 (char*)Bs16 + c * 16);
                    }
                } else {
#pragma unroll
                    for (int i = 0; i < 8; ++i) {
                        int c = i * 256 + tid;
                        int r = c >> 4;
                        int sb = ((c & 15) * 16) ^ ((r & 7) << 4);
                        lds_cp16(fcw32 + (size_t)(col0 + r) * 1024 + k0 + (sb >> 2),
                                 (char*)Bs32 + c * 16);
                    }
                }
                __syncthreads();
#pragma unroll
                for (int s = 0; s < 2; ++s) {
                    short8 af[4], bfr[4];
#pragma unroll
                    for (int m = 0; m < 4; ++m) {
                        int row = rw0 + m * 16 + lr;
                        int cb = (s * 64 + lg * 16) ^ ((row & 7) << 4);
                        af[m] = *(const short8*)((const char*)As + row * 128 + cb);
                    }
#pragma unroll
                    for (int n = 0; n < 4; ++n) {
                        int row = cw0 + n * 16 + lr;
                        if (BF16W) {
                            int cb = (s * 64 + lg * 16) ^ ((row & 7) << 4);
                            bfr[n] = *(const short8*)((const char*)Bs16 + row * 128 + cb);
                        } else {
                            int base = s * 128 + lg * 32;
                            int cb0 = base ^ ((row & 7) << 4);
                            int cb1 = (base + 16) ^ ((row & 7) << 4);
                            float4 fA = *(const float4*)((const char*)Bs32 + row * 256 + cb0);
                            float4 fB = *(const float4*)((const char*)Bs32 + row * 256 + cb1);
                            union { unsigned short us[8]; short8 s8; } t;
                            t.us[0] = __bfloat16_as_ushort(__float2bfloat16(fA.x));
                            t.us[1] = __bfloat16_as_ushort(__float2bfloat16(fA.y));
                            t.us[2] = __bfloat16_as_ushort(__float2bfloat16(fA.z));
                            t.us[3] = __bfloat16_as_ushort(__float2bfloat16(fA.w));
                            t.us[4] = __bfloat16_as_ushort(__float2bfloat16(fB.x));
                            t.us[5] = __bfloat16_as_ushort(__float2bfloat16(fB.y));
                            t.us[6] = __bfloat16_as_ushort(__float2bfloat16(fB.z));
                            t.us[7] = __bfloat16_as_ushort(__float2bfloat16(fB.w));
                            bfr[n] = t.s8;
                        }
                    }
#pragma unroll
                    for (int m = 0; m < 4; ++m)
#pragma unroll
                        for (int n = 0; n < 4; ++n)
                            acc[m][n] = __builtin_amdgcn_mfma_f32_16x16x32_bf16(bfr[n], af[m], acc[m][n], 0, 0, 0);
                }
                __syncthreads();
            }
#pragma unroll
            for (int m = 0; m < 4; ++m) {
#pragma unroll
                for (int n = 0; n < 4; ++n) {
                    int r = row0 + rw0 + m * 16 + lr;
                    int c0b = col0 + cw0 + n * 16 + lg * 4;
                    f32x4 v = acc[m][n] + *(const f32x4*)(fcb + c0b);
                    int b = r & 31, t = r >> 5;
                    *(f32x4*)(outp + ((size_t)b * T_ + t) * (size_t)V_ + c0b) = v;
                }
            }
        };

        // phase 1 (FC blocks only): paced static sweep, 3 owned by-columns
        if (blockIdx.x >= NBS) {
            const int fcid = blockIdx.x - NBS;
            for (int bx = 0; bx < 32; ++bx) {
                wait_flags_sleep(flags, 2 * 64, 64, 4 * bx + 8);
#pragma unroll
                for (int j = 0; j < 3; ++j)
                    fc_tile(bx, fcid * 3 + j);
            }
        } else if (BF16W) {
            wait_flags_sleep(aux + 64, 0, 64, 1);   // stairs need fcwB before phase 2
        }

        // phase 2: cleanup queue over by 192..249 in 8-bx same-by chunks
        for (;;) {
            __syncthreads();
            if (tid == 0)
                *jslot = (int)__hip_atomic_fetch_add((unsigned*)aux, 1u,
                                                     __ATOMIC_RELAXED, __HIP_MEMORY_SCOPE_AGENT);
            __syncthreads();
            int job = *jslot;
            if (job >= NJOBS2) break;
            int by = 192 + (job >> 2);
            int bx0 = (job & 3) * 8;
            for (int e = 0; e < 8; ++e) {
                int bx = bx0 + e;
                wait_flags_sleep(flags, 2 * 64, 64, 4 * bx + 8);
                fc_tile(bx, by);
            }
        }
    }
}

// ---------------------------------------------------------------------------
extern "C" void kernel_launch(void* const* d_in, const int* in_sizes, int n_in,
                              void* d_out, int out_size, void* d_ws, size_t ws_size,
                              hipStream_t stream) {
    const int* tok = (const int*)d_in[0];
    const int* cat = (const int*)d_in[1];
    const float* h1 = (const float*)d_in[3];
    const float* h2 = (const float*)d_in[4];
    const float* h3 = (const float*)d_in[5];
    const float* wemb = (const float*)d_in[6];
    const float* cemb = (const float*)d_in[7];
    const float* Wih[3] = {(const float*)d_in[8], (const float*)d_in[12], (const float*)d_in[16]};
    const float* Whh[3] = {(const float*)d_in[9], (const float*)d_in[13], (const float*)d_in[17]};
    const float* bih[3] = {(const float*)d_in[10], (const float*)d_in[14], (const float*)d_in[18]};
    const float* bhh[3] = {(const float*)d_in[11], (const float*)d_in[15], (const float*)d_in[19]};
    const float* fcw = (const float*)d_in[20];
    const float* fcb = (const float*)d_in[21];
    float* out = (float*)d_out;

    // ws layout (bytes): base ~136.7 MB; fcwB (64MB) appended only if ws allows.
    // aux (wq + padded fcflags) and padded flags live in the dead Xbf region.
    char* ws = (char*)d_ws;
    unsigned* C3 = (unsigned*)ws;                       // 0 .. 8,388,608
    bf16* Xbf = (bf16*)(ws + 8388608);
    int* aux = (int*)(ws + 8388608);                    // wq @0, fcflags @64+i*FS
    int* flags = (int*)(ws + 8388608) + 4096;           // 192 x FS ints (24,576 B)
    bf16* WihB1 = (bf16*)(ws + 25165824);
    float* GI0 = (float*)(ws + 37748736);
    bf16* WihB2 = (bf16*)(ws + 88080384);
    bf16* WihB3 = (bf16*)(ws + 94371840);
    bf16* WhhB1 = (bf16*)(ws + 100663296);
    bf16* WhhB2 = (bf16*)(ws + 106954752);
    bf16* WhhB3 = (bf16*)(ws + 113246208);
    unsigned* Hx = (unsigned*)(ws + 119537664);
    unsigned* C1 = (unsigned*)(ws + 119931904);
    unsigned* C2 = (unsigned*)(ws + 128320512);
    bf16* fcwB = (bf16*)(ws + 136709120);               // .. 202,245,120
    const bool bigws = (ws_size >= 202245120ull);

    convW_kernel<<<10752, 256, 0, stream>>>(Wih[0], WihB1, Wih[1], WihB2, Wih[2], WihB3,
                                            Whh[0], WhhB1, Whh[1], WhhB2, Whh[2], WhhB3);
    embed_kernel<<<T_ * B_, 256, 0, stream>>>(tok, cat, wemb, cemb, Xbf);
    gemm_bt<<<dim3(32, 24), 256, 0, stream>>>(Xbf, WihB1, bih[0], GI0, 4096, 3072, 2048);
    stair_init<<<192, 256, 0, stream>>>(h1, h2, h3, Hx, flags, aux);
    float* out_tail = out + (size_t)B_ * T_ * V_;
    if (bigws)
        stair_fc<1><<<256, 256, 0, stream>>>(GI0, WihB2, WihB3, WhhB1, WhhB2, WhhB3,
                                             bih[1], bih[2], bhh[0], bhh[1], bhh[2],
                                             h1, h2, h3, Hx, flags, aux, C1, C2, C3, out_tail,
                                             fcw, fcwB, fcb, out);
    else
        stair_fc<0><<<256, 256, 0, stream>>>(GI0, WihB2, WihB3, WhhB1, WhhB2, WhhB3,
                                             bih[1], bih[2], bhh[0], bhh[1], bhh[2],
                                             h1, h2, h3, Hx, flags, aux, C1, C2, C3, out_tail,
                                             fcw, fcwB, fcb, out);
}

// Round 14
// 2032.350 us; speedup vs baseline: 1.1549x; 1.1549x over previous
//
#include <hip/hip_runtime.h>
#include <hip/hip_bf16.h>
#include <cstdint>
#include <cstddef>

#define B_ 32
#define T_ 128
#define H_ 1024
#define V_ 32000
#define NBS 192            // staircase blocks (3 layers x 64 groups); +64 FC blocks
#define NITER (T_ + 4)     // lag-2 staircase: layer l at tl = s - 2l
#define FS 32              // flag stride (ints) = 128B per flag line
#define NJOBS2 744         // phase-2: by 64..249 (186 cols) x 4 chunks of 8 bx

using bf16 = __hip_bfloat16;
typedef __attribute__((ext_vector_type(8))) short short8;
typedef __attribute__((ext_vector_type(4))) float f32x4;

union v16 { f32x4 f; short8 s; };

__device__ __forceinline__ float bf2f(unsigned short u) {
    return __uint_as_float(((unsigned)u) << 16);
}

__device__ __forceinline__ void lds_cp16(const void* g, void* l) {
    __builtin_amdgcn_global_load_lds(
        (const __attribute__((address_space(1))) unsigned int*)g,
        (__attribute__((address_space(3))) unsigned int*)l, 16, 0, 0);
}

// coherence-point (LLC) 16B vector load, agent/system scope, pipelined
__device__ __forceinline__ f32x4 coh_ld16(const void* p) {
    f32x4 r;
    asm volatile("global_load_dwordx4 %0, %1, off sc0 sc1"
                 : "=v"(r) : "v"(p) : "memory");
    return r;
}
// coherence-point dword store
__device__ __forceinline__ void coh_st4(void* p, unsigned v) {
    asm volatile("global_store_dword %0, %1, off sc0 sc1" :: "v"(p), "v"(v) : "memory");
}
// non-temporal 16B store (FC output stream; keep LLC clean)
__device__ __forceinline__ void nt_st16(void* p, f32x4 v) {
    asm volatile("global_store_dwordx4 %0, %1, off nt" :: "v"(p), "v"(v) : "memory");
}
// drain asm loads/stores, pin scheduling (rule 18)
__device__ __forceinline__ void wait_vm0() {
    asm volatile("s_waitcnt vmcnt(0)" ::: "memory");
    __builtin_amdgcn_sched_barrier(0);
}

// ---------------------------------------------------------------------------
__global__ __launch_bounds__(256)
void convW_kernel(const float* __restrict__ s0, bf16* __restrict__ d0,
                  const float* __restrict__ s1, bf16* __restrict__ d1,
                  const float* __restrict__ s2, bf16* __restrict__ d2,
                  const float* __restrict__ s3, bf16* __restrict__ d3,
                  const float* __restrict__ s4, bf16* __restrict__ d4,
                  const float* __restrict__ s5, bf16* __restrict__ d5) {
    const int bid = blockIdx.x;
    const float* src; bf16* dst; int i8;
    if (bid < 3072) { src = s0; dst = d0; i8 = bid * 256 + threadIdx.x; }
    else {
        int r = (bid - 3072) / 1536;
        int rb = (bid - 3072) % 1536;
        i8 = rb * 256 + threadIdx.x;
        switch (r) {
            case 0: src = s1; dst = d1; break;
            case 1: src = s2; dst = d2; break;
            case 2: src = s3; dst = d3; break;
            case 3: src = s4; dst = d4; break;
            default: src = s5; dst = d5; break;
        }
    }
    const float4* s = (const float4*)(src + (size_t)i8 * 8);
    float4 a = s[0], b = s[1];
    ushort4 o0, o1;
    o0.x = __bfloat16_as_ushort(__float2bfloat16(a.x));
    o0.y = __bfloat16_as_ushort(__float2bfloat16(a.y));
    o0.z = __bfloat16_as_ushort(__float2bfloat16(a.z));
    o0.w = __bfloat16_as_ushort(__float2bfloat16(a.w));
    o1.x = __bfloat16_as_ushort(__float2bfloat16(b.x));
    o1.y = __bfloat16_as_ushort(__float2bfloat16(b.y));
    o1.z = __bfloat16_as_ushort(__float2bfloat16(b.z));
    o1.w = __bfloat16_as_ushort(__float2bfloat16(b.w));
    ((ushort4*)(dst + (size_t)i8 * 8))[0] = o0;
    ((ushort4*)(dst + (size_t)i8 * 8))[1] = o1;
}

// ---------------------------------------------------------------------------
__global__ __launch_bounds__(256)
void embed_kernel(const int* __restrict__ tok, const int* __restrict__ cat,
                  const float* __restrict__ wemb, const float* __restrict__ cemb,
                  bf16* __restrict__ X) {
    const int tb = blockIdx.x;
    const int t = tb >> 5, b = tb & 31;
    const int token = tok[b * T_ + t];
    const int c = cat[b * T_ + t];
    const int i = threadIdx.x;
    const float* src = (i < 128) ? (wemb + (size_t)token * H_ + (size_t)i * 8)
                                 : (cemb + (size_t)c * H_ + (size_t)(i - 128) * 8);
    float4 a = ((const float4*)src)[0];
    float4 bv = ((const float4*)src)[1];
    ushort4 o0, o1;
    o0.x = __bfloat16_as_ushort(__float2bfloat16(a.x));
    o0.y = __bfloat16_as_ushort(__float2bfloat16(a.y));
    o0.z = __bfloat16_as_ushort(__float2bfloat16(a.z));
    o0.w = __bfloat16_as_ushort(__float2bfloat16(a.w));
    o1.x = __bfloat16_as_ushort(__float2bfloat16(bv.x));
    o1.y = __bfloat16_as_ushort(__float2bfloat16(bv.y));
    o1.z = __bfloat16_as_ushort(__float2bfloat16(bv.z));
    o1.w = __bfloat16_as_ushort(__float2bfloat16(bv.w));
    ushort4* d = (ushort4*)(X + (size_t)tb * 2 * H_ + (size_t)i * 8);
    d[0] = o0;
    d[1] = o1;
}

// ---------------------------------------------------------------------------
__global__ __launch_bounds__(256)
void gemm_bt(const bf16* __restrict__ A, const bf16* __restrict__ Bm,
             const float* __restrict__ bias, float* __restrict__ Cf,
             int M, int N, int K) {
    __shared__ __align__(16) bf16 As[128 * 64];
    __shared__ __align__(16) bf16 Bs[128 * 64];
    const int tid = threadIdx.x;
    const int lane = tid & 63;
    const int wid = tid >> 6;
    const int row0 = blockIdx.x * 128;
    const int col0 = blockIdx.y * 128;
    const int rw0 = (wid >> 1) * 64;
    const int cw0 = (wid & 1) * 64;
    const int lr = lane & 15;
    const int lg = lane >> 4;
    f32x4 acc[4][4] = {};
    const int nk = K >> 6;
    for (int kt = 0; kt < nk; ++kt) {
        const int k0 = kt * 64;
#pragma unroll
        for (int i = 0; i < 4; ++i) {
            int c = i * 256 + tid;
            int r = c >> 3;
            int kc = (c & 7) * 8;
            lds_cp16(A + (size_t)(row0 + r) * K + (k0 + kc), (void*)(As + c * 8));
            lds_cp16(Bm + (size_t)(col0 + r) * K + (k0 + kc), (void*)(Bs + c * 8));
        }
        __syncthreads();
#pragma unroll
        for (int s = 0; s < 2; ++s) {
            short8 af[4], bfr[4];
#pragma unroll
            for (int m = 0; m < 4; ++m)
                af[m] = *(const short8*)(As + (rw0 + m * 16 + lr) * 64 + s * 32 + lg * 8);
#pragma unroll
            for (int n = 0; n < 4; ++n)
                bfr[n] = *(const short8*)(Bs + (cw0 + n * 16 + lr) * 64 + s * 32 + lg * 8);
#pragma unroll
            for (int m = 0; m < 4; ++m)
#pragma unroll
                for (int n = 0; n < 4; ++n)
                    acc[m][n] = __builtin_amdgcn_mfma_f32_16x16x32_bf16(bfr[n], af[m], acc[m][n], 0, 0, 0);
        }
        __syncthreads();
    }
#pragma unroll
    for (int m = 0; m < 4; ++m) {
#pragma unroll
        for (int n = 0; n < 4; ++n) {
            int r = row0 + rw0 + m * 16 + lr;
            int c0b = col0 + cw0 + n * 16 + lg * 4;
            f32x4 v = acc[m][n] + *(const f32x4*)(bias + c0b);
            *(f32x4*)(Cf + (size_t)r * N + c0b) = v;
        }
    }
}

// ---------------------------------------------------------------------------
__global__ __launch_bounds__(256)
void stair_init(const float* __restrict__ h1, const float* __restrict__ h2,
                const float* __restrict__ h3, unsigned* __restrict__ Hx,
                int* __restrict__ flags, int* __restrict__ aux) {
    int idx = blockIdx.x * 256 + threadIdx.x;   // < 3*16384
    if (idx < NBS * FS) flags[idx] = 0;
    if (idx < 64 * FS + 64) aux[idx] = 0;
    int l = idx >> 14, r = idx & 16383;
    int b = r >> 9, k = r & 511;
    const float* h = (l == 0 ? h1 : (l == 1 ? h2 : h3));
    unsigned lo = __bfloat16_as_ushort(__float2bfloat16(h[b * H_ + 2 * k]));
    unsigned hi = __bfloat16_as_ushort(__float2bfloat16(h[b * H_ + 2 * k + 1]));
    Hx[((l * 2 + 0) * 32 + b) * 512 + k] = lo | (hi << 16);
}

// ---------------------------------------------------------------------------
__device__ __forceinline__ void wait_flags(const int* flags, int base, int nflags,
                                           int thr, int own) {
    const int tid = threadIdx.x;
    int mine = 1;
    const int* fp = nullptr;
    int idx = base + tid;
    if (tid < nflags) { fp = flags + (size_t)idx * FS; mine = (idx == own) ? 1 : 0; }
    int done = 0;
    do {
        if (!mine)
            mine = (__hip_atomic_load(fp, __ATOMIC_RELAXED, __HIP_MEMORY_SCOPE_AGENT) >= thr);
        done = __syncthreads_and(mine);
    } while (!done);
}

__device__ __forceinline__ void wait_flags_sleep(const int* flags, int base, int nflags,
                                                 int thr) {
    const int tid = threadIdx.x;
    int mine = 1;
    const int* fp = nullptr;
    if (tid < nflags) { fp = flags + (size_t)(base + tid) * FS; mine = 0; }
    int done = 0;
    do {
        if (!mine)
            mine = (__hip_atomic_load(fp, __ATOMIC_RELAXED, __HIP_MEMORY_SCOPE_AGENT) >= thr);
        done = __syncthreads_and(mine);
        if (!done) __builtin_amdgcn_s_sleep(16);
    } while (!done);
}

// ---------------------------------------------------------------------------
template<int BF16W>
__global__ __launch_bounds__(256, 1)
void stair_fc(const float* __restrict__ GI0,
              const bf16* __restrict__ Wih2, const bf16* __restrict__ Wih3,
              const bf16* __restrict__ Whh1, const bf16* __restrict__ Whh2,
              const bf16* __restrict__ Whh3,
              const float* __restrict__ bih2, const float* __restrict__ bih3,
              const float* __restrict__ bhh1, const float* __restrict__ bhh2,
              const float* __restrict__ bhh3,
              const float* __restrict__ h1, const float* __restrict__ h2,
              const float* __restrict__ h3,
              unsigned* __restrict__ Hx, int* __restrict__ flags,
              int* __restrict__ aux,
              unsigned* __restrict__ c1, unsigned* __restrict__ c2,
              unsigned* __restrict__ c3, float* __restrict__ outt,
              const float* __restrict__ fcw32, bf16* __restrict__ fcwB,
              const float* __restrict__ fcb, float* __restrict__ outp) {
    __shared__ __align__(16) char smem[127488];
    const int tid = threadIdx.x;
    const int lane = tid & 63;
    const int wid = tid >> 6;
    const int lr = lane & 15;
    const int lg = lane >> 4;

    if (blockIdx.x < NBS) {
        // ================= staircase path =================
        float* PlH = (float*)smem;
        float* PlI = (float*)(smem + 24576);
        float* RrH = (float*)(smem + 49152);
        float* RrI = (float*)(smem + 55296);
        char* cbuf = smem + 61440;                    // 32 rows x 2064B
        const int l = blockIdx.x >> 6;
        const int u0 = (blockIdx.x & 63) * 16;
        const int kbase = wid * 256;

        const bf16* Whh = (l == 0) ? Whh1 : ((l == 1) ? Whh2 : Whh3);
        const bf16* Wih = (l == 1) ? Wih2 : Wih3;
        const float* bhh = (l == 0) ? bhh1 : ((l == 1) ? bhh2 : bhh3);
        const float* bih = (l == 1) ? bih2 : bih3;
        const float* hinit = (l == 0) ? h1 : ((l == 1) ? h2 : h3);
        const unsigned short* wh = (const unsigned short*)Whh;
        const unsigned short* wi = (const unsigned short*)Wih;
        const unsigned* Cin = (l == 1) ? c1 : c2;
        unsigned* Cout = (l == 0) ? c1 : c2;

        short8 wfH[3][8];
#pragma unroll
        for (int g = 0; g < 3; ++g)
#pragma unroll
            for (int kf = 0; kf < 8; ++kf)
                wfH[g][kf] = *(const short8*)(wh + (size_t)(g * H_ + u0 + lr) * H_ + kbase + kf * 32 + lg * 8);

        const int gb = tid >> 3;
        const int up = tid & 7;
        float hold0 = hinit[(size_t)gb * H_ + u0 + 2 * up];
        float hold1 = hinit[(size_t)gb * H_ + u0 + 2 * up + 1];

        float bhA = bhh[((tid >> 3) >> 4) * H_ + u0 + ((tid >> 3) & 15)];
        float bhB = (tid < 128) ? bhh[(((tid + 256) >> 3) >> 4) * H_ + u0 + (((tid + 256) >> 3) & 15)] : 0.f;
        float biA = 0.f, biB = 0.f;
        if (l > 0) {
            biA = bih[((tid >> 3) >> 4) * H_ + u0 + ((tid >> 3) & 15)];
            if (tid < 128) biB = bih[(((tid + 256) >> 3) >> 4) * H_ + u0 + (((tid + 256) >> 3) & 15)];
        }

        for (int s = 0; s < NITER; ++s) {
            const int tl = s - 2 * l;
            const bool act = (tl >= 0) && (tl < T_);
            const int tln = tl + 1;
            const bool pre = (l > 0) && (tln >= 0) && (tln < T_);
            float g0r = 0.f, g0z = 0.f, g0n = 0.f, g1r = 0.f, g1z = 0.f, g1n = 0.f;
            if (l == 0 && act) {
                const float* gi = GI0 + ((size_t)tl * B_ + gb) * 3072 + u0 + 2 * up;
                g0r = gi[0];    g1r = gi[1];
                g0z = gi[1024]; g1z = gi[1025];
                g0n = gi[2048]; g1n = gi[2049];
            }
            // top-of-loop: own-layer RAW/WAR only (64 flags)
            wait_flags(flags, 64 * l, 64, s, blockIdx.x);

            f32x4 accH[2][3] = {};
            f32x4 accI[2][3] = {};
            f32x4 h4[16];
            if (act) {
                const char* hp0 = (const char*)(Hx + (size_t)((l * 2 + (tl & 1)) * 32 + lr) * 512);
                const char* hp1 = (const char*)(Hx + (size_t)((l * 2 + (tl & 1)) * 32 + 16 + lr) * 512);
#pragma unroll
                for (int kf = 0; kf < 8; ++kf) {
                    const int off = ((kbase >> 1) + kf * 16 + lg * 4) * 4;
                    h4[kf] = coh_ld16(hp0 + off);
                    h4[8 + kf] = coh_ld16(hp1 + off);
                }
                if (l > 0) {
#pragma unroll
                    for (int kf = 0; kf < 8; ++kf) {
                        const int kb2 = kbase * 2 + kf * 64 + lg * 16;
                        short8 cv0 = *(const short8*)(cbuf + lr * 2064 + kb2);
                        short8 cv1 = *(const short8*)(cbuf + (16 + lr) * 2064 + kb2);
                        const int ko = kbase + kf * 32 + lg * 8;
#pragma unroll
                        for (int g = 0; g < 3; ++g) {
                            short8 w = *(const short8*)(wi + (size_t)(g * H_ + u0 + lr) * H_ + ko);
                            accI[0][g] = __builtin_amdgcn_mfma_f32_16x16x32_bf16(cv0, w, accI[0][g], 0, 0, 0);
                            accI[1][g] = __builtin_amdgcn_mfma_f32_16x16x32_bf16(cv1, w, accI[1][g], 0, 0, 0);
                        }
                    }
                }
                wait_vm0();   // h4 ready
#pragma unroll
                for (int kf = 0; kf < 8; ++kf) {
                    v16 a0, a1;
                    a0.f = h4[kf];
                    a1.f = h4[8 + kf];
#pragma unroll
                    for (int g = 0; g < 3; ++g) {
                        accH[0][g] = __builtin_amdgcn_mfma_f32_16x16x32_bf16(a0.s, wfH[g][kf], accH[0][g], 0, 0, 0);
                        accH[1][g] = __builtin_amdgcn_mfma_f32_16x16x32_bf16(a1.s, wfH[g][kf], accH[1][g], 0, 0, 0);
                    }
                }
#pragma unroll
                for (int m = 0; m < 2; ++m)
#pragma unroll
                    for (int g = 0; g < 3; ++g) {
                        int col = g * 16 + lr;
                        int key = (col + (col >> 3)) & 7;
                        int byte_off = wid * 6144 + col * 128 + (((m * 16 + lg * 4) * 4) ^ (key << 4));
                        *(f32x4*)((char*)PlH + byte_off) = accH[m][g];
                        if (l > 0) *(f32x4*)((char*)PlI + byte_off) = accI[m][g];
                    }
            }
            __syncthreads();
            // l-1 wait only gates the prefetch (off the h-RAW path)
            f32x4 ct4[16];
            if (pre) {
                wait_flags(flags, 64 * (l - 1), 64, s, -1);
                const char* cp0 = (const char*)(Cin + (size_t)tln * (B_ * 512) + (size_t)lr * 512);
                const char* cp1 = (const char*)(Cin + (size_t)tln * (B_ * 512) + (size_t)(16 + lr) * 512);
#pragma unroll
                for (int kf = 0; kf < 8; ++kf) {
                    const int off = ((kbase >> 1) + kf * 16 + lg * 4) * 4;
                    ct4[kf] = coh_ld16(cp0 + off);
                    ct4[8 + kf] = coh_ld16(cp1 + off);
                }
            }
            if (act) {
#pragma unroll
                for (int it = 0; it < 2; ++it) {
                    int task = tid + it * 256;
                    if (task < 384) {
                        int col = task >> 3, bq = task & 7;
                        int key = (col + (col >> 3)) & 7;
                        int boff = col * 128 + ((bq * 16) ^ (key << 4));
                        float bh = (it == 0) ? bhA : bhB;
                        f32x4 s0 = *(const f32x4*)((const char*)PlH + boff);
                        f32x4 s1 = *(const f32x4*)((const char*)PlH + 6144 + boff);
                        f32x4 s2 = *(const f32x4*)((const char*)PlH + 12288 + boff);
                        f32x4 s3 = *(const f32x4*)((const char*)PlH + 18432 + boff);
                        f32x4 sv = (s0 + s1) + (s2 + s3);
                        sv[0] += bh; sv[1] += bh; sv[2] += bh; sv[3] += bh;
                        *(f32x4*)((char*)RrH + boff) = sv;
                        if (l > 0) {
                            float bi = (it == 0) ? biA : biB;
                            f32x4 t0 = *(const f32x4*)((const char*)PlI + boff);
                            f32x4 t1 = *(const f32x4*)((const char*)PlI + 6144 + boff);
                            f32x4 t2 = *(const f32x4*)((const char*)PlI + 12288 + boff);
                            f32x4 t3 = *(const f32x4*)((const char*)PlI + 18432 + boff);
                            f32x4 tv = (t0 + t1) + (t2 + t3);
                            tv[0] += bi; tv[1] += bi; tv[2] += bi; tv[3] += bi;
                            *(f32x4*)((char*)RrI + boff) = tv;
                        }
                    }
                }
            }
            __syncthreads();
            if (act) {
                float hn[2];
#pragma unroll
                for (int e = 0; e < 2; ++e) {
                    int u = 2 * up + e;
                    int colR = u, colZ = 16 + u, colN = 32 + u;
                    int keyR = (colR + (colR >> 3)) & 7;
                    int keyZ = (colZ + (colZ >> 3)) & 7;
                    int keyN = (colN + (colN >> 3)) & 7;
                    float ghr = *(const float*)((const char*)RrH + colR * 128 + ((gb * 4) ^ (keyR << 4)));
                    float ghz = *(const float*)((const char*)RrH + colZ * 128 + ((gb * 4) ^ (keyZ << 4)));
                    float ghn = *(const float*)((const char*)RrH + colN * 128 + ((gb * 4) ^ (keyN << 4)));
                    float gir, giz, gin;
                    if (l == 0) {
                        gir = (e == 0) ? g0r : g1r;
                        giz = (e == 0) ? g0z : g1z;
                        gin = (e == 0) ? g0n : g1n;
                    } else {
                        gir = *(const float*)((const char*)RrI + colR * 128 + ((gb * 4) ^ (keyR << 4)));
                        giz = *(const float*)((const char*)RrI + colZ * 128 + ((gb * 4) ^ (keyZ << 4)));
                        gin = *(const float*)((const char*)RrI + colN * 128 + ((gb * 4) ^ (keyN << 4)));
                    }
                    float holdv = (e == 0) ? hold0 : hold1;
                    float rr = 1.f / (1.f + expf(-(gir + ghr)));
                    float zz = 1.f / (1.f + expf(-(giz + ghz)));
                    float nn = tanhf(gin + rr * ghn);
                    float hnew = (1.f - zz) * nn + zz * holdv;
                    if (e == 0) hold0 = hnew; else hold1 = hnew;
                    hn[e] = hnew;
                }
                unsigned lo = __bfloat16_as_ushort(__float2bfloat16(hn[0]));
                unsigned hi = __bfloat16_as_ushort(__float2bfloat16(hn[1]));
                unsigned pk = lo | (hi << 16);
                coh_st4(Hx + (size_t)((l * 2 + ((tl + 1) & 1)) * 32 + gb) * 512 + (u0 >> 1) + up, pk);
                if (l < 2)
                    coh_st4(Cout + ((size_t)tl * B_ + gb) * 512 + (u0 >> 1) + up, pk);
                else
                    coh_st4(c3 + ((size_t)tl * B_ + gb) * 512 + (u0 >> 1) + up, pk);
            }
            wait_vm0();        // drain h/C stores + prefetch loads
            __syncthreads();
            if (tid == 0)
                coh_st4(&flags[(size_t)blockIdx.x * FS], (unsigned)(s + 1));
            if (pre) {
#pragma unroll
                for (int kf = 0; kf < 8; ++kf) {
                    const int kb2 = kbase * 2 + kf * 64 + lg * 16;
                    *(f32x4*)(cbuf + lr * 2064 + kb2) = ct4[kf];
                    *(f32x4*)(cbuf + (16 + lr) * 2064 + kb2) = ct4[8 + kf];
                }
            }
        }
        outt[(size_t)l * 32768 + (size_t)(tid >> 3) * H_ + u0 + 2 * (tid & 7)] = hold0;
        outt[(size_t)l * 32768 + (size_t)(tid >> 3) * H_ + u0 + 2 * (tid & 7) + 1] = hold1;
        __syncthreads();
    } else {
        // FC prologue: convert this block's 500-row fcw slice to bf16 (LLC stores)
        if (BF16W) {
            const int fcid = blockIdx.x - NBS;
            const float2* src = (const float2*)(fcw32 + (size_t)fcid * 500 * 1024);
            unsigned* dst = (unsigned*)fcwB + (size_t)fcid * 500 * 512;
            for (int i = tid; i < 500 * 512; i += 256) {
                float2 v = src[i];
                unsigned pk = (unsigned)__bfloat16_as_ushort(__float2bfloat16(v.x)) |
                              ((unsigned)__bfloat16_as_ushort(__float2bfloat16(v.y)) << 16);
                coh_st4(dst + i, pk);
            }
            wait_vm0();
            __syncthreads();
            if (tid == 0)
                coh_st4(&aux[64 + (blockIdx.x - NBS) * FS], 1u);
            wait_flags_sleep(aux + 64, 0, 64, 1);
        }
    }

    // ===================== shared FC tile machinery =====================
    {
        bf16* As = (bf16*)smem;
        bf16* Bs16 = (bf16*)(smem + 16384);
        float* Bs32 = (float*)(smem + 16384);
        int* jslot = (int*)(smem + 126976);
        const bf16* Abase = (const bf16*)c3;
        const bf16* fcwBr = (const bf16*)fcwB;
        const int rw0 = (wid >> 1) * 64;
        const int cw0 = (wid & 1) * 64;

        auto fc_tile = [&](int bx, int by) {
            const int row0 = bx * 128, col0 = by * 128;
            f32x4 acc[4][4] = {};
            for (int kt = 0; kt < 16; ++kt) {
                const int k0 = kt * 64;
#pragma unroll
                for (int i = 0; i < 4; ++i) {
                    int c = i * 256 + tid;
                    int r = c >> 3;
                    int sb = ((c & 7) * 16) ^ ((r & 7) << 4);
                    lds_cp16(Abase + (size_t)(row0 + r) * 1024 + k0 + (sb >> 1),
                             (char*)As + c * 16);
                }
                if (BF16W) {
#pragma unroll
                    for (int i = 0; i < 4; ++i) {
                        int c = i * 256 + tid;
                        int r = c >> 3;
                        int sb = ((c & 7) * 16) ^ ((r & 7) << 4);
                        lds_cp16(fcwBr + (size_t)(col0 + r) * 1024 + k0 + (sb >> 1),
                                 (char*)Bs16 + c * 16);
                    }
                } else {
#pragma unroll
                    for (int i = 0; i < 8; ++i) {
                        int c = i * 256 + tid;
                        int r = c >> 4;
                        int sb = ((c & 15) * 16) ^ ((r & 7) << 4);
                        lds_cp16(fcw32 + (size_t)(col0 + r) * 1024 + k0 + (sb >> 2),
                                 (char*)Bs32 + c * 16);
                    }
                }
                __syncthreads();
#pragma unroll
                for (int s = 0; s < 2; ++s) {
                    short8 af[4], bfr[4];
#pragma unroll
                    for (int m = 0; m < 4; ++m) {
                        int row = rw0 + m * 16 + lr;
                        int cb = (s * 64 + lg * 16) ^ ((row & 7) << 4);
                        af[m] = *(const short8*)((const char*)As + row * 128 + cb);
                    }
#pragma unroll
                    for (int n = 0; n < 4; ++n) {
                        int row = cw0 + n * 16 + lr;
                        if (BF16W) {
                            int cb = (s * 64 + lg * 16) ^ ((row & 7) << 4);
                            bfr[n] = *(const short8*)((const char*)Bs16 + row * 128 + cb);
                        } else {
                            int base = s * 128 + lg * 32;
                            int cb0 = base ^ ((row & 7) << 4);
                            int cb1 = (base + 16) ^ ((row & 7) << 4);
                            float4 fA = *(const float4*)((const char*)Bs32 + row * 256 + cb0);
                            float4 fB = *(const float4*)((const char*)Bs32 + row * 256 + cb1);
                            union { unsigned short us[8]; short8 s8; } t;
                            t.us[0] = __bfloat16_as_ushort(__float2bfloat16(fA.x));
                            t.us[1] = __bfloat16_as_ushort(__float2bfloat16(fA.y));
                            t.us[2] = __bfloat16_as_ushort(__float2bfloat16(fA.z));
                            t.us[3] = __bfloat16_as_ushort(__float2bfloat16(fA.w));
                            t.us[4] = __bfloat16_as_ushort(__float2bfloat16(fB.x));
                            t.us[5] = __bfloat16_as_ushort(__float2bfloat16(fB.y));
                            t.us[6] = __bfloat16_as_ushort(__float2bfloat16(fB.z));
                            t.us[7] = __bfloat16_as_ushort(__float2bfloat16(fB.w));
                            bfr[n] = t.s8;
                        }
                    }
#pragma unroll
                    for (int m = 0; m < 4; ++m)
#pragma unroll
                        for (int n = 0; n < 4; ++n)
                            acc[m][n] = __builtin_amdgcn_mfma_f32_16x16x32_bf16(bfr[n], af[m], acc[m][n], 0, 0, 0);
                }
                __syncthreads();
            }
#pragma unroll
            for (int m = 0; m < 4; ++m) {
#pragma unroll
                for (int n = 0; n < 4; ++n) {
                    int r = row0 + rw0 + m * 16 + lr;
                    int c0b = col0 + cw0 + n * 16 + lg * 4;
                    f32x4 v = acc[m][n] + *(const f32x4*)(fcb + c0b);
                    int b = r & 31, t = r >> 5;
                    nt_st16(outp + ((size_t)b * T_ + t) * (size_t)V_ + c0b, v);
                }
            }
        };

        // phase 1 (FC blocks only): ONE owned by-column, bx-paced sweep
        if (blockIdx.x >= NBS) {
            const int fcid = blockIdx.x - NBS;   // by = fcid (0..63)
            for (int bx = 0; bx < 32; ++bx) {
                wait_flags_sleep(flags, 2 * 64, 64, 4 * bx + 8);
                fc_tile(bx, fcid);
            }
        } else if (BF16W) {
            wait_flags_sleep(aux + 64, 0, 64, 1);
        }

        // phase 2: queue over by 64..249 in 8-bx same-by chunks
        for (;;) {
            __syncthreads();
            if (tid == 0)
                *jslot = (int)__hip_atomic_fetch_add((unsigned*)aux, 1u,
                                                     __ATOMIC_RELAXED, __HIP_MEMORY_SCOPE_AGENT);
            __syncthreads();
            int job = *jslot;
            if (job >= NJOBS2) break;
            int by = 64 + (job >> 2);
            int bx0 = (job & 3) * 8;
            for (int e = 0; e < 8; ++e) {
                int bx = bx0 + e;
                wait_flags_sleep(flags, 2 * 64, 64, 4 * bx + 8);
                fc_tile(bx, by);
            }
        }
    }
}

// ---------------------------------------------------------------------------
extern "C" void kernel_launch(void* const* d_in, const int* in_sizes, int n_in,
                              void* d_out, int out_size, void* d_ws, size_t ws_size,
                              hipStream_t stream) {
    const int* tok = (const int*)d_in[0];
    const int* cat = (const int*)d_in[1];
    const float* h1 = (const float*)d_in[3];
    const float* h2 = (const float*)d_in[4];
    const float* h3 = (const float*)d_in[5];
    const float* wemb = (const float*)d_in[6];
    const float* cemb = (const float*)d_in[7];
    const float* Wih[3] = {(const float*)d_in[8], (const float*)d_in[12], (const float*)d_in[16]};
    const float* Whh[3] = {(const float*)d_in[9], (const float*)d_in[13], (const float*)d_in[17]};
    const float* bih[3] = {(const float*)d_in[10], (const float*)d_in[14], (const float*)d_in[18]};
    const float* bhh[3] = {(const float*)d_in[11], (const float*)d_in[15], (const float*)d_in[19]};
    const float* fcw = (const float*)d_in[20];
    const float* fcb = (const float*)d_in[21];
    float* out = (float*)d_out;

    char* ws = (char*)d_ws;
    unsigned* C3 = (unsigned*)ws;                       // 0 .. 8,388,608
    bf16* Xbf = (bf16*)(ws + 8388608);
    int* aux = (int*)(ws + 8388608);                    // overlays dead Xbf
    int* flags = (int*)(ws + 8388608) + 4096;
    bf16* WihB1 = (bf16*)(ws + 25165824);
    float* GI0 = (float*)(ws + 37748736);
    bf16* WihB2 = (bf16*)(ws + 88080384);
    bf16* WihB3 = (bf16*)(ws + 94371840);
    bf16* WhhB1 = (bf16*)(ws + 100663296);
    bf16* WhhB2 = (bf16*)(ws + 106954752);
    bf16* WhhB3 = (bf16*)(ws + 113246208);
    unsigned* Hx = (unsigned*)(ws + 119537664);
    unsigned* C1 = (unsigned*)(ws + 119931904);
    unsigned* C2 = (unsigned*)(ws + 128320512);
    bf16* fcwB = (bf16*)(ws + 136709120);               // .. 202,245,120
    const bool bigws = (ws_size >= 202245120ull);

    convW_kernel<<<10752, 256, 0, stream>>>(Wih[0], WihB1, Wih[1], WihB2, Wih[2], WihB3,
                                            Whh[0], WhhB1, Whh[1], WhhB2, Whh[2], WhhB3);
    embed_kernel<<<T_ * B_, 256, 0, stream>>>(tok, cat, wemb, cemb, Xbf);
    gemm_bt<<<dim3(32, 24), 256, 0, stream>>>(Xbf, WihB1, bih[0], GI0, 4096, 3072, 2048);
    stair_init<<<192, 256, 0, stream>>>(h1, h2, h3, Hx, flags, aux);
    float* out_tail = out + (size_t)B_ * T_ * V_;
    if (bigws)
        stair_fc<1><<<256, 256, 0, stream>>>(GI0, WihB2, WihB3, WhhB1, WhhB2, WhhB3,
                                             bih[1], bih[2], bhh[0], bhh[1], bhh[2],
                                             h1, h2, h3, Hx, flags, aux, C1, C2, C3, out_tail,
                                             fcw, fcwB, fcb, out);
    else
        stair_fc<0><<<256, 256, 0, stream>>>(GI0, WihB2, WihB3, WhhB1, WhhB2, WhhB3,
                                             bih[1], bih[2], bhh[0], bhh[1], bhh[2],
                                             h1, h2, h3, Hx, flags, aux, C1, C2, C3, out_tail,
                                             fcw, fcwB, fcb, out);
}

// Round 15
// 1892.597 us; speedup vs baseline: 1.2401x; 1.0738x over previous
//
#include <hip/hip_runtime.h>
#include <hip/hip_bf16.h>
#include <cstdint>
#include <cstddef>

#define B_ 32
#define T_ 128
#define H_ 1024
#define V_ 32000
#define NBS 192            // staircase blocks (3 layers x 64 groups); +64 FC blocks
#define NITER (T_ + 4)     // lag-2 staircase: layer l at tl = s - 2l
#define FS 32              // flag stride (ints) = 128B per flag line
#define NJOBS 1000         // unified FC queue: 4 chunks x 250 by-columns

using bf16 = __hip_bfloat16;
typedef __attribute__((ext_vector_type(8))) short short8;
typedef __attribute__((ext_vector_type(4))) float f32x4;

union v16 { f32x4 f; short8 s; };

__device__ __forceinline__ float bf2f(unsigned short u) {
    return __uint_as_float(((unsigned)u) << 16);
}

__device__ __forceinline__ void lds_cp16(const void* g, void* l) {
    __builtin_amdgcn_global_load_lds(
        (const __attribute__((address_space(1))) unsigned int*)g,
        (__attribute__((address_space(3))) unsigned int*)l, 16, 0, 0);
}

// coherence-point (LLC) 16B vector load, agent/system scope, pipelined
__device__ __forceinline__ f32x4 coh_ld16(const void* p) {
    f32x4 r;
    asm volatile("global_load_dwordx4 %0, %1, off sc0 sc1"
                 : "=v"(r) : "v"(p) : "memory");
    return r;
}
// coherence-point dword store
__device__ __forceinline__ void coh_st4(void* p, unsigned v) {
    asm volatile("global_store_dword %0, %1, off sc0 sc1" :: "v"(p), "v"(v) : "memory");
}
// non-temporal 16B store (FC output stream; keep LLC clean)
__device__ __forceinline__ void nt_st16(void* p, f32x4 v) {
    asm volatile("global_store_dwordx4 %0, %1, off nt" :: "v"(p), "v"(v) : "memory");
}
// drain asm loads/stores, pin scheduling (rule 18)
__device__ __forceinline__ void wait_vm0() {
    asm volatile("s_waitcnt vmcnt(0)" ::: "memory");
    __builtin_amdgcn_sched_barrier(0);
}

// ---------------------------------------------------------------------------
__global__ __launch_bounds__(256)
void convW_kernel(const float* __restrict__ s0, bf16* __restrict__ d0,
                  const float* __restrict__ s1, bf16* __restrict__ d1,
                  const float* __restrict__ s2, bf16* __restrict__ d2,
                  const float* __restrict__ s3, bf16* __restrict__ d3,
                  const float* __restrict__ s4, bf16* __restrict__ d4,
                  const float* __restrict__ s5, bf16* __restrict__ d5) {
    const int bid = blockIdx.x;
    const float* src; bf16* dst; int i8;
    if (bid < 3072) { src = s0; dst = d0; i8 = bid * 256 + threadIdx.x; }
    else {
        int r = (bid - 3072) / 1536;
        int rb = (bid - 3072) % 1536;
        i8 = rb * 256 + threadIdx.x;
        switch (r) {
            case 0: src = s1; dst = d1; break;
            case 1: src = s2; dst = d2; break;
            case 2: src = s3; dst = d3; break;
            case 3: src = s4; dst = d4; break;
            default: src = s5; dst = d5; break;
        }
    }
    const float4* s = (const float4*)(src + (size_t)i8 * 8);
    float4 a = s[0], b = s[1];
    ushort4 o0, o1;
    o0.x = __bfloat16_as_ushort(__float2bfloat16(a.x));
    o0.y = __bfloat16_as_ushort(__float2bfloat16(a.y));
    o0.z = __bfloat16_as_ushort(__float2bfloat16(a.z));
    o0.w = __bfloat16_as_ushort(__float2bfloat16(a.w));
    o1.x = __bfloat16_as_ushort(__float2bfloat16(b.x));
    o1.y = __bfloat16_as_ushort(__float2bfloat16(b.y));
    o1.z = __bfloat16_as_ushort(__float2bfloat16(b.z));
    o1.w = __bfloat16_as_ushort(__float2bfloat16(b.w));
    ((ushort4*)(dst + (size_t)i8 * 8))[0] = o0;
    ((ushort4*)(dst + (size_t)i8 * 8))[1] = o1;
}

// ---------------------------------------------------------------------------
__global__ __launch_bounds__(256)
void embed_kernel(const int* __restrict__ tok, const int* __restrict__ cat,
                  const float* __restrict__ wemb, const float* __restrict__ cemb,
                  bf16* __restrict__ X) {
    const int tb = blockIdx.x;
    const int t = tb >> 5, b = tb & 31;
    const int token = tok[b * T_ + t];
    const int c = cat[b * T_ + t];
    const int i = threadIdx.x;
    const float* src = (i < 128) ? (wemb + (size_t)token * H_ + (size_t)i * 8)
                                 : (cemb + (size_t)c * H_ + (size_t)(i - 128) * 8);
    float4 a = ((const float4*)src)[0];
    float4 bv = ((const float4*)src)[1];
    ushort4 o0, o1;
    o0.x = __bfloat16_as_ushort(__float2bfloat16(a.x));
    o0.y = __bfloat16_as_ushort(__float2bfloat16(a.y));
    o0.z = __bfloat16_as_ushort(__float2bfloat16(a.z));
    o0.w = __bfloat16_as_ushort(__float2bfloat16(a.w));
    o1.x = __bfloat16_as_ushort(__float2bfloat16(bv.x));
    o1.y = __bfloat16_as_ushort(__float2bfloat16(bv.y));
    o1.z = __bfloat16_as_ushort(__float2bfloat16(bv.z));
    o1.w = __bfloat16_as_ushort(__float2bfloat16(bv.w));
    ushort4* d = (ushort4*)(X + (size_t)tb * 2 * H_ + (size_t)i * 8);
    d[0] = o0;
    d[1] = o1;
}

// ---------------------------------------------------------------------------
__global__ __launch_bounds__(256)
void gemm_bt(const bf16* __restrict__ A, const bf16* __restrict__ Bm,
             const float* __restrict__ bias, float* __restrict__ Cf,
             int M, int N, int K) {
    __shared__ __align__(16) bf16 As[128 * 64];
    __shared__ __align__(16) bf16 Bs[128 * 64];
    const int tid = threadIdx.x;
    const int lane = tid & 63;
    const int wid = tid >> 6;
    const int row0 = blockIdx.x * 128;
    const int col0 = blockIdx.y * 128;
    const int rw0 = (wid >> 1) * 64;
    const int cw0 = (wid & 1) * 64;
    const int lr = lane & 15;
    const int lg = lane >> 4;
    f32x4 acc[4][4] = {};
    const int nk = K >> 6;
    for (int kt = 0; kt < nk; ++kt) {
        const int k0 = kt * 64;
#pragma unroll
        for (int i = 0; i < 4; ++i) {
            int c = i * 256 + tid;
            int r = c >> 3;
            int kc = (c & 7) * 8;
            lds_cp16(A + (size_t)(row0 + r) * K + (k0 + kc), (void*)(As + c * 8));
            lds_cp16(Bm + (size_t)(col0 + r) * K + (k0 + kc), (void*)(Bs + c * 8));
        }
        __syncthreads();
#pragma unroll
        for (int s = 0; s < 2; ++s) {
            short8 af[4], bfr[4];
#pragma unroll
            for (int m = 0; m < 4; ++m)
                af[m] = *(const short8*)(As + (rw0 + m * 16 + lr) * 64 + s * 32 + lg * 8);
#pragma unroll
            for (int n = 0; n < 4; ++n)
                bfr[n] = *(const short8*)(Bs + (cw0 + n * 16 + lr) * 64 + s * 32 + lg * 8);
#pragma unroll
            for (int m = 0; m < 4; ++m)
#pragma unroll
                for (int n = 0; n < 4; ++n)
                    acc[m][n] = __builtin_amdgcn_mfma_f32_16x16x32_bf16(bfr[n], af[m], acc[m][n], 0, 0, 0);
        }
        __syncthreads();
    }
#pragma unroll
    for (int m = 0; m < 4; ++m) {
#pragma unroll
        for (int n = 0; n < 4; ++n) {
            int r = row0 + rw0 + m * 16 + lr;
            int c0b = col0 + cw0 + n * 16 + lg * 4;
            f32x4 v = acc[m][n] + *(const f32x4*)(bias + c0b);
            *(f32x4*)(Cf + (size_t)r * N + c0b) = v;
        }
    }
}

// ---------------------------------------------------------------------------
__global__ __launch_bounds__(256)
void stair_init(const float* __restrict__ h1, const float* __restrict__ h2,
                const float* __restrict__ h3, unsigned* __restrict__ Hx,
                int* __restrict__ flags, int* __restrict__ aux) {
    int idx = blockIdx.x * 256 + threadIdx.x;   // < 3*16384
    if (idx < NBS * FS) flags[idx] = 0;
    if (idx < 64 * FS + 64) aux[idx] = 0;
    int l = idx >> 14, r = idx & 16383;
    int b = r >> 9, k = r & 511;
    const float* h = (l == 0 ? h1 : (l == 1 ? h2 : h3));
    unsigned lo = __bfloat16_as_ushort(__float2bfloat16(h[b * H_ + 2 * k]));
    unsigned hi = __bfloat16_as_ushort(__float2bfloat16(h[b * H_ + 2 * k + 1]));
    Hx[((l * 2 + 0) * 32 + b) * 512 + k] = lo | (hi << 16);
}

// ---------------------------------------------------------------------------
__device__ __forceinline__ void wait_flags(const int* flags, int base, int nflags,
                                           int thr, int own) {
    const int tid = threadIdx.x;
    int mine = 1;
    const int* fp = nullptr;
    int idx = base + tid;
    if (tid < nflags) { fp = flags + (size_t)idx * FS; mine = (idx == own) ? 1 : 0; }
    int done = 0;
    do {
        if (!mine)
            mine = (__hip_atomic_load(fp, __ATOMIC_RELAXED, __HIP_MEMORY_SCOPE_AGENT) >= thr);
        done = __syncthreads_and(mine);
    } while (!done);
}

__device__ __forceinline__ void wait_flags_sleep(const int* flags, int base, int nflags,
                                                 int thr) {
    const int tid = threadIdx.x;
    int mine = 1;
    const int* fp = nullptr;
    if (tid < nflags) { fp = flags + (size_t)(base + tid) * FS; mine = 0; }
    int done = 0;
    do {
        if (!mine)
            mine = (__hip_atomic_load(fp, __ATOMIC_RELAXED, __HIP_MEMORY_SCOPE_AGENT) >= thr);
        done = __syncthreads_and(mine);
        if (!done) __builtin_amdgcn_s_sleep(16);
    } while (!done);
}

// ---------------------------------------------------------------------------
template<int BF16W>
__global__ __launch_bounds__(256, 1)
void stair_fc(const float* __restrict__ GI0,
              const bf16* __restrict__ Wih2, const bf16* __restrict__ Wih3,
              const bf16* __restrict__ Whh1, const bf16* __restrict__ Whh2,
              const bf16* __restrict__ Whh3,
              const float* __restrict__ bih2, const float* __restrict__ bih3,
              const float* __restrict__ bhh1, const float* __restrict__ bhh2,
              const float* __restrict__ bhh3,
              const float* __restrict__ h1, const float* __restrict__ h2,
              const float* __restrict__ h3,
              unsigned* __restrict__ Hx, int* __restrict__ flags,
              int* __restrict__ aux,
              unsigned* __restrict__ c1, unsigned* __restrict__ c2,
              unsigned* __restrict__ c3, float* __restrict__ outt,
              const float* __restrict__ fcw32, bf16* __restrict__ fcwB,
              const float* __restrict__ fcb, float* __restrict__ outp) {
    __shared__ __align__(16) char smem[127488];
    const int tid = threadIdx.x;
    const int lane = tid & 63;
    const int wid = tid >> 6;
    const int lr = lane & 15;
    const int lg = lane >> 4;

    if (blockIdx.x < NBS) {
        // ================= staircase path =================
        float* PlH = (float*)smem;
        float* PlI = (float*)(smem + 24576);
        float* RrH = (float*)(smem + 49152);
        float* RrI = (float*)(smem + 55296);
        char* cbuf = smem + 61440;                    // 32 rows x 2064B
        const int l = blockIdx.x >> 6;
        const int u0 = (blockIdx.x & 63) * 16;
        const int kbase = wid * 256;

        const bf16* Whh = (l == 0) ? Whh1 : ((l == 1) ? Whh2 : Whh3);
        const bf16* Wih = (l == 1) ? Wih2 : Wih3;
        const float* bhh = (l == 0) ? bhh1 : ((l == 1) ? bhh2 : bhh3);
        const float* bih = (l == 1) ? bih2 : bih3;
        const float* hinit = (l == 0) ? h1 : ((l == 1) ? h2 : h3);
        const unsigned short* wh = (const unsigned short*)Whh;
        const unsigned short* wi = (const unsigned short*)Wih;
        const unsigned* Cin = (l == 1) ? c1 : c2;
        unsigned* Cout = (l == 0) ? c1 : c2;

        short8 wfH[3][8];
#pragma unroll
        for (int g = 0; g < 3; ++g)
#pragma unroll
            for (int kf = 0; kf < 8; ++kf)
                wfH[g][kf] = *(const short8*)(wh + (size_t)(g * H_ + u0 + lr) * H_ + kbase + kf * 32 + lg * 8);

        const int gb = tid >> 3;
        const int up = tid & 7;
        float hold0 = hinit[(size_t)gb * H_ + u0 + 2 * up];
        float hold1 = hinit[(size_t)gb * H_ + u0 + 2 * up + 1];

        float bhA = bhh[((tid >> 3) >> 4) * H_ + u0 + ((tid >> 3) & 15)];
        float bhB = (tid < 128) ? bhh[(((tid + 256) >> 3) >> 4) * H_ + u0 + (((tid + 256) >> 3) & 15)] : 0.f;
        float biA = 0.f, biB = 0.f;
        if (l > 0) {
            biA = bih[((tid >> 3) >> 4) * H_ + u0 + ((tid >> 3) & 15)];
            if (tid < 128) biB = bih[(((tid + 256) >> 3) >> 4) * H_ + u0 + (((tid + 256) >> 3) & 15)];
        }

        for (int s = 0; s < NITER; ++s) {
            const int tl = s - 2 * l;
            const bool act = (tl >= 0) && (tl < T_);
            const int tln = tl + 1;
            const bool pre = (l > 0) && (tln >= 0) && (tln < T_);
            float g0r = 0.f, g0z = 0.f, g0n = 0.f, g1r = 0.f, g1z = 0.f, g1n = 0.f;
            if (l == 0 && act) {
                const float* gi = GI0 + ((size_t)tl * B_ + gb) * 3072 + u0 + 2 * up;
                g0r = gi[0];    g1r = gi[1];
                g0z = gi[1024]; g1z = gi[1025];
                g0n = gi[2048]; g1n = gi[2049];
            }
            // top-of-loop: own-layer RAW/WAR only (64 flags)
            wait_flags(flags, 64 * l, 64, s, blockIdx.x);

            f32x4 accH[2][3] = {};
            f32x4 accI[2][3] = {};
            f32x4 h4[16];
            if (act) {
                const char* hp0 = (const char*)(Hx + (size_t)((l * 2 + (tl & 1)) * 32 + lr) * 512);
                const char* hp1 = (const char*)(Hx + (size_t)((l * 2 + (tl & 1)) * 32 + 16 + lr) * 512);
#pragma unroll
                for (int kf = 0; kf < 8; ++kf) {
                    const int off = ((kbase >> 1) + kf * 16 + lg * 4) * 4;
                    h4[kf] = coh_ld16(hp0 + off);
                    h4[8 + kf] = coh_ld16(hp1 + off);
                }
                if (l > 0) {
#pragma unroll
                    for (int kf = 0; kf < 8; ++kf) {
                        const int kb2 = kbase * 2 + kf * 64 + lg * 16;
                        short8 cv0 = *(const short8*)(cbuf + lr * 2064 + kb2);
                        short8 cv1 = *(const short8*)(cbuf + (16 + lr) * 2064 + kb2);
                        const int ko = kbase + kf * 32 + lg * 8;
#pragma unroll
                        for (int g = 0; g < 3; ++g) {
                            short8 w = *(const short8*)(wi + (size_t)(g * H_ + u0 + lr) * H_ + ko);
                            accI[0][g] = __builtin_amdgcn_mfma_f32_16x16x32_bf16(cv0, w, accI[0][g], 0, 0, 0);
                            accI[1][g] = __builtin_amdgcn_mfma_f32_16x16x32_bf16(cv1, w, accI[1][g], 0, 0, 0);
                        }
                    }
                }
                wait_vm0();   // h4 ready
#pragma unroll
                for (int kf = 0; kf < 8; ++kf) {
                    v16 a0, a1;
                    a0.f = h4[kf];
                    a1.f = h4[8 + kf];
#pragma unroll
                    for (int g = 0; g < 3; ++g) {
                        accH[0][g] = __builtin_amdgcn_mfma_f32_16x16x32_bf16(a0.s, wfH[g][kf], accH[0][g], 0, 0, 0);
                        accH[1][g] = __builtin_amdgcn_mfma_f32_16x16x32_bf16(a1.s, wfH[g][kf], accH[1][g], 0, 0, 0);
                    }
                }
#pragma unroll
                for (int m = 0; m < 2; ++m)
#pragma unroll
                    for (int g = 0; g < 3; ++g) {
                        int col = g * 16 + lr;
                        int key = (col + (col >> 3)) & 7;
                        int byte_off = wid * 6144 + col * 128 + (((m * 16 + lg * 4) * 4) ^ (key << 4));
                        *(f32x4*)((char*)PlH + byte_off) = accH[m][g];
                        if (l > 0) *(f32x4*)((char*)PlI + byte_off) = accI[m][g];
                    }
            }
            __syncthreads();
            // l-1 wait only gates the prefetch (off the h-RAW path)
            f32x4 ct4[16];
            if (pre) {
                wait_flags(flags, 64 * (l - 1), 64, s, -1);
                const char* cp0 = (const char*)(Cin + (size_t)tln * (B_ * 512) + (size_t)lr * 512);
                const char* cp1 = (const char*)(Cin + (size_t)tln * (B_ * 512) + (size_t)(16 + lr) * 512);
#pragma unroll
                for (int kf = 0; kf < 8; ++kf) {
                    const int off = ((kbase >> 1) + kf * 16 + lg * 4) * 4;
                    ct4[kf] = coh_ld16(cp0 + off);
                    ct4[8 + kf] = coh_ld16(cp1 + off);
                }
            }
            if (act) {
#pragma unroll
                for (int it = 0; it < 2; ++it) {
                    int task = tid + it * 256;
                    if (task < 384) {
                        int col = task >> 3, bq = task & 7;
                        int key = (col + (col >> 3)) & 7;
                        int boff = col * 128 + ((bq * 16) ^ (key << 4));
                        float bh = (it == 0) ? bhA : bhB;
                        f32x4 s0 = *(const f32x4*)((const char*)PlH + boff);
                        f32x4 s1 = *(const f32x4*)((const char*)PlH + 6144 + boff);
                        f32x4 s2 = *(const f32x4*)((const char*)PlH + 12288 + boff);
                        f32x4 s3 = *(const f32x4*)((const char*)PlH + 18432 + boff);
                        f32x4 sv = (s0 + s1) + (s2 + s3);
                        sv[0] += bh; sv[1] += bh; sv[2] += bh; sv[3] += bh;
                        *(f32x4*)((char*)RrH + boff) = sv;
                        if (l > 0) {
                            float bi = (it == 0) ? biA : biB;
                            f32x4 t0 = *(const f32x4*)((const char*)PlI + boff);
                            f32x4 t1 = *(const f32x4*)((const char*)PlI + 6144 + boff);
                            f32x4 t2 = *(const f32x4*)((const char*)PlI + 12288 + boff);
                            f32x4 t3 = *(const f32x4*)((const char*)PlI + 18432 + boff);
                            f32x4 tv = (t0 + t1) + (t2 + t3);
                            tv[0] += bi; tv[1] += bi; tv[2] += bi; tv[3] += bi;
                            *(f32x4*)((char*)RrI + boff) = tv;
                        }
                    }
                }
            }
            __syncthreads();
            if (act) {
                float hn[2];
#pragma unroll
                for (int e = 0; e < 2; ++e) {
                    int u = 2 * up + e;
                    int colR = u, colZ = 16 + u, colN = 32 + u;
                    int keyR = (colR + (colR >> 3)) & 7;
                    int keyZ = (colZ + (colZ >> 3)) & 7;
                    int keyN = (colN + (colN >> 3)) & 7;
                    float ghr = *(const float*)((const char*)RrH + colR * 128 + ((gb * 4) ^ (keyR << 4)));
                    float ghz = *(const float*)((const char*)RrH + colZ * 128 + ((gb * 4) ^ (keyZ << 4)));
                    float ghn = *(const float*)((const char*)RrH + colN * 128 + ((gb * 4) ^ (keyN << 4)));
                    float gir, giz, gin;
                    if (l == 0) {
                        gir = (e == 0) ? g0r : g1r;
                        giz = (e == 0) ? g0z : g1z;
                        gin = (e == 0) ? g0n : g1n;
                    } else {
                        gir = *(const float*)((const char*)RrI + colR * 128 + ((gb * 4) ^ (keyR << 4)));
                        giz = *(const float*)((const char*)RrI + colZ * 128 + ((gb * 4) ^ (keyZ << 4)));
                        gin = *(const float*)((const char*)RrI + colN * 128 + ((gb * 4) ^ (keyN << 4)));
                    }
                    float holdv = (e == 0) ? hold0 : hold1;
                    float rr = 1.f / (1.f + expf(-(gir + ghr)));
                    float zz = 1.f / (1.f + expf(-(giz + ghz)));
                    float nn = tanhf(gin + rr * ghn);
                    float hnew = (1.f - zz) * nn + zz * holdv;
                    if (e == 0) hold0 = hnew; else hold1 = hnew;
                    hn[e] = hnew;
                }
                unsigned lo = __bfloat16_as_ushort(__float2bfloat16(hn[0]));
                unsigned hi = __bfloat16_as_ushort(__float2bfloat16(hn[1]));
                unsigned pk = lo | (hi << 16);
                coh_st4(Hx + (size_t)((l * 2 + ((tl + 1) & 1)) * 32 + gb) * 512 + (u0 >> 1) + up, pk);
                if (l < 2)
                    coh_st4(Cout + ((size_t)tl * B_ + gb) * 512 + (u0 >> 1) + up, pk);
                else
                    coh_st4(c3 + ((size_t)tl * B_ + gb) * 512 + (u0 >> 1) + up, pk);
            }
            wait_vm0();        // drain h/C stores + prefetch loads
            __syncthreads();
            if (tid == 0)
                coh_st4(&flags[(size_t)blockIdx.x * FS], (unsigned)(s + 1));
            if (pre) {
#pragma unroll
                for (int kf = 0; kf < 8; ++kf) {
                    const int kb2 = kbase * 2 + kf * 64 + lg * 16;
                    *(f32x4*)(cbuf + lr * 2064 + kb2) = ct4[kf];
                    *(f32x4*)(cbuf + (16 + lr) * 2064 + kb2) = ct4[8 + kf];
                }
            }
        }
        outt[(size_t)l * 32768 + (size_t)(tid >> 3) * H_ + u0 + 2 * (tid & 7)] = hold0;
        outt[(size_t)l * 32768 + (size_t)(tid >> 3) * H_ + u0 + 2 * (tid & 7) + 1] = hold1;
        __syncthreads();
        if (BF16W) wait_flags_sleep(aux + 64, 0, 64, 1);   // fcwB ready (long since)
    } else {
        // FC prologue: convert this block's 500-row fcw slice to bf16 (LLC stores)
        if (BF16W) {
            const int fcid = blockIdx.x - NBS;
            const float2* src = (const float2*)(fcw32 + (size_t)fcid * 500 * 1024);
            unsigned* dst = (unsigned*)fcwB + (size_t)fcid * 500 * 512;
            for (int i = tid; i < 500 * 512; i += 256) {
                float2 v = src[i];
                unsigned pk = (unsigned)__bfloat16_as_ushort(__float2bfloat16(v.x)) |
                              ((unsigned)__bfloat16_as_ushort(__float2bfloat16(v.y)) << 16);
                coh_st4(dst + i, pk);
            }
            wait_vm0();
            __syncthreads();
            if (tid == 0)
                coh_st4(&aux[64 + (blockIdx.x - NBS) * FS], 1u);
            wait_flags_sleep(aux + 64, 0, 64, 1);
        }
    }

    // ============== unified frontier-paced FC queue (all blocks) ==============
    {
        bf16* As = (bf16*)smem;
        bf16* Bs16 = (bf16*)(smem + 16384);
        float* Bs32 = (float*)(smem + 16384);
        int* jslot = (int*)(smem + 126976);
        const bf16* Abase = (const bf16*)c3;
        const bf16* fcwBr = (const bf16*)fcwB;
        const int rw0 = (wid >> 1) * 64;
        const int cw0 = (wid & 1) * 64;

        auto fc_tile = [&](int bx, int by) {
            const int row0 = bx * 128, col0 = by * 128;
            f32x4 acc[4][4] = {};
            for (int kt = 0; kt < 16; ++kt) {
                const int k0 = kt * 64;
#pragma unroll
                for (int i = 0; i < 4; ++i) {
                    int c = i * 256 + tid;
                    int r = c >> 3;
                    int sb = ((c & 7) * 16) ^ ((r & 7) << 4);
                    lds_cp16(Abase + (size_t)(row0 + r) * 1024 + k0 + (sb >> 1),
                             (char*)As + c * 16);
                }
                if (BF16W) {
#pragma unroll
                    for (int i = 0; i < 4; ++i) {
                        int c = i * 256 + tid;
                        int r = c >> 3;
                        int sb = ((c & 7) * 16) ^ ((r & 7) << 4);
                        lds_cp16(fcwBr + (size_t)(col0 + r) * 1024 + k0 + (sb >> 1),
                                 (char*)Bs16 + c * 16);
                    }
                } else {
#pragma unroll
                    for (int i = 0; i < 8; ++i) {
                        int c = i * 256 + tid;
                        int r = c >> 4;
                        int sb = ((c & 15) * 16) ^ ((r & 7) << 4);
                        lds_cp16(fcw32 + (size_t)(col0 + r) * 1024 + k0 + (sb >> 2),
                                 (char*)Bs32 + c * 16);
                    }
                }
                __syncthreads();
#pragma unroll
                for (int s = 0; s < 2; ++s) {
                    short8 af[4], bfr[4];
#pragma unroll
                    for (int m = 0; m < 4; ++m) {
                        int row = rw0 + m * 16 + lr;
                        int cb = (s * 64 + lg * 16) ^ ((row & 7) << 4);
                        af[m] = *(const short8*)((const char*)As + row * 128 + cb);
                    }
#pragma unroll
                    for (int n = 0; n < 4; ++n) {
                        int row = cw0 + n * 16 + lr;
                        if (BF16W) {
                            int cb = (s * 64 + lg * 16) ^ ((row & 7) << 4);
                            bfr[n] = *(const short8*)((const char*)Bs16 + row * 128 + cb);
                        } else {
                            int base = s * 128 + lg * 32;
                            int cb0 = base ^ ((row & 7) << 4);
                            int cb1 = (base + 16) ^ ((row & 7) << 4);
                            float4 fA = *(const float4*)((const char*)Bs32 + row * 256 + cb0);
                            float4 fB = *(const float4*)((const char*)Bs32 + row * 256 + cb1);
                            union { unsigned short us[8]; short8 s8; } t;
                            t.us[0] = __bfloat16_as_ushort(__float2bfloat16(fA.x));
                            t.us[1] = __bfloat16_as_ushort(__float2bfloat16(fA.y));
                            t.us[2] = __bfloat16_as_ushort(__float2bfloat16(fA.z));
                            t.us[3] = __bfloat16_as_ushort(__float2bfloat16(fA.w));
                            t.us[4] = __bfloat16_as_ushort(__float2bfloat16(fB.x));
                            t.us[5] = __bfloat16_as_ushort(__float2bfloat16(fB.y));
                            t.us[6] = __bfloat16_as_ushort(__float2bfloat16(fB.z));
                            t.us[7] = __bfloat16_as_ushort(__float2bfloat16(fB.w));
                            bfr[n] = t.s8;
                        }
                    }
#pragma unroll
                    for (int m = 0; m < 4; ++m)
#pragma unroll
                        for (int n = 0; n < 4; ++n)
                            acc[m][n] = __builtin_amdgcn_mfma_f32_16x16x32_bf16(bfr[n], af[m], acc[m][n], 0, 0, 0);
                }
                __syncthreads();
            }
#pragma unroll
            for (int m = 0; m < 4; ++m) {
#pragma unroll
                for (int n = 0; n < 4; ++n) {
                    int r = row0 + rw0 + m * 16 + lr;
                    int c0b = col0 + cw0 + n * 16 + lg * 4;
                    f32x4 v = acc[m][n] + *(const f32x4*)(fcb + c0b);
                    int b = r & 31, t = r >> 5;
                    nt_st16(outp + ((size_t)b * T_ + t) * (size_t)V_ + c0b, v);
                }
            }
        };

        // job j -> chunk = j/250 (bx0 = chunk*8), by = j%250; per-tile flag gate
        for (;;) {
            __syncthreads();
            if (tid == 0)
                *jslot = (int)__hip_atomic_fetch_add((unsigned*)aux, 1u,
                                                     __ATOMIC_RELAXED, __HIP_MEMORY_SCOPE_AGENT);
            __syncthreads();
            int job = *jslot;
            if (job >= NJOBS) break;
            int cidx = job / 250;
            int by = job - cidx * 250;
            int bx0 = cidx * 8;
            for (int e = 0; e < 8; ++e) {
                int bx = bx0 + e;
                wait_flags_sleep(flags, 2 * 64, 64, 4 * bx + 8);
                fc_tile(bx, by);
            }
        }
    }
}

// ---------------------------------------------------------------------------
extern "C" void kernel_launch(void* const* d_in, const int* in_sizes, int n_in,
                              void* d_out, int out_size, void* d_ws, size_t ws_size,
                              hipStream_t stream) {
    const int* tok = (const int*)d_in[0];
    const int* cat = (const int*)d_in[1];
    const float* h1 = (const float*)d_in[3];
    const float* h2 = (const float*)d_in[4];
    const float* h3 = (const float*)d_in[5];
    const float* wemb = (const float*)d_in[6];
    const float* cemb = (const float*)d_in[7];
    const float* Wih[3] = {(const float*)d_in[8], (const float*)d_in[12], (const float*)d_in[16]};
    const float* Whh[3] = {(const float*)d_in[9], (const float*)d_in[13], (const float*)d_in[17]};
    const float* bih[3] = {(const float*)d_in[10], (const float*)d_in[14], (const float*)d_in[18]};
    const float* bhh[3] = {(const float*)d_in[11], (const float*)d_in[15], (const float*)d_in[19]};
    const float* fcw = (const float*)d_in[20];
    const float* fcb = (const float*)d_in[21];
    float* out = (float*)d_out;

    char* ws = (char*)d_ws;
    unsigned* C3 = (unsigned*)ws;                       // 0 .. 8,388,608
    bf16* Xbf = (bf16*)(ws + 8388608);
    int* aux = (int*)(ws + 8388608);                    // overlays dead Xbf
    int* flags = (int*)(ws + 8388608) + 4096;
    bf16* WihB1 = (bf16*)(ws + 25165824);
    float* GI0 = (float*)(ws + 37748736);
    bf16* WihB2 = (bf16*)(ws + 88080384);
    bf16* WihB3 = (bf16*)(ws + 94371840);
    bf16* WhhB1 = (bf16*)(ws + 100663296);
    bf16* WhhB2 = (bf16*)(ws + 106954752);
    bf16* WhhB3 = (bf16*)(ws + 113246208);
    unsigned* Hx = (unsigned*)(ws + 119537664);
    unsigned* C1 = (unsigned*)(ws + 119931904);
    unsigned* C2 = (unsigned*)(ws + 128320512);
    bf16* fcwB = (bf16*)(ws + 136709120);               // .. 202,245,120
    const bool bigws = (ws_size >= 202245120ull);

    convW_kernel<<<10752, 256, 0, stream>>>(Wih[0], WihB1, Wih[1], WihB2, Wih[2], WihB3,
                                            Whh[0], WhhB1, Whh[1], WhhB2, Whh[2], WhhB3);
    embed_kernel<<<T_ * B_, 256, 0, stream>>>(tok, cat, wemb, cemb, Xbf);
    gemm_bt<<<dim3(32, 24), 256, 0, stream>>>(Xbf, WihB1, bih[0], GI0, 4096, 3072, 2048);
    stair_init<<<192, 256, 0, stream>>>(h1, h2, h3, Hx, flags, aux);
    float* out_tail = out + (size_t)B_ * T_ * V_;
    if (bigws)
        stair_fc<1><<<256, 256, 0, stream>>>(GI0, WihB2, WihB3, WhhB1, WhhB2, WhhB3,
                                             bih[1], bih[2], bhh[0], bhh[1], bhh[2],
                                             h1, h2, h3, Hx, flags, aux, C1, C2, C3, out_tail,
                                             fcw, fcwB, fcb, out);
    else
        stair_fc<0><<<256, 256, 0, stream>>>(GI0, WihB2, WihB3, WhhB1, WhhB2, WhhB3,
                                             bih[1], bih[2], bhh[0], bhh[1], bhh[2],
                                             h1, h2, h3, Hx, flags, aux, C1, C2, C3, out_tail,
                                             fcw, fcwB, fcb, out);
}

// Round 17
// 1875.650 us; speedup vs baseline: 1.2513x; 1.0090x over previous
//
#include <hip/hip_runtime.h>
#include <hip/hip_bf16.h>
#include <cstdint>
#include <cstddef>

#define B_ 32
#define T_ 128
#define H_ 1024
#define V_ 32000
#define NBS 192            // staircase blocks (3 layers x 64 groups); +64 FC blocks
#define NITER (T_ + 4)     // lag-2 staircase: layer l at tl = s - 2l
#define FS 32              // flag stride (ints) = 128B per flag line
#define NJOBS 1000         // unified FC queue: 4 chunks x 250 by-columns

using bf16 = __hip_bfloat16;
typedef __attribute__((ext_vector_type(8))) short short8;
typedef __attribute__((ext_vector_type(4))) float f32x4;

union v16 { f32x4 f; short8 s; };

__device__ __forceinline__ float bf2f(unsigned short u) {
    return __uint_as_float(((unsigned)u) << 16);
}

__device__ __forceinline__ void lds_cp16(const void* g, void* l) {
    __builtin_amdgcn_global_load_lds(
        (const __attribute__((address_space(1))) unsigned int*)g,
        (__attribute__((address_space(3))) unsigned int*)l, 16, 0, 0);
}

// coherence-point (LLC) 16B vector load, agent/system scope, pipelined
// (used only AFTER an atomic-load flag observation -- never polled)
__device__ __forceinline__ f32x4 coh_ld16(const void* p) {
    f32x4 r;
    asm volatile("global_load_dwordx4 %0, %1, off sc0 sc1"
                 : "=v"(r) : "v"(p) : "memory");
    return r;
}
// coherence-point dword store
__device__ __forceinline__ void coh_st4(void* p, unsigned v) {
    asm volatile("global_store_dword %0, %1, off sc0 sc1" :: "v"(p), "v"(v) : "memory");
}
// non-temporal 16B store (FC output stream; keep LLC clean)
__device__ __forceinline__ void nt_st16(void* p, f32x4 v) {
    asm volatile("global_store_dwordx4 %0, %1, off nt" :: "v"(p), "v"(v) : "memory");
}
// drain asm loads/stores, pin scheduling (rule 18)
__device__ __forceinline__ void wait_vm0() {
    asm volatile("s_waitcnt vmcnt(0)" ::: "memory");
    __builtin_amdgcn_sched_barrier(0);
}

// ---------------------------------------------------------------------------
// merged prologue: blocks [0,10752) convert the 6 GRU weight matrices to bf16;
// blocks [10752,14848) build X = [bf16(word_emb[token]) | bf16(cat_emb[cat])]
__global__ __launch_bounds__(256)
void prep_kernel(const float* __restrict__ s0, bf16* __restrict__ d0,
                 const float* __restrict__ s1, bf16* __restrict__ d1,
                 const float* __restrict__ s2, bf16* __restrict__ d2,
                 const float* __restrict__ s3, bf16* __restrict__ d3,
                 const float* __restrict__ s4, bf16* __restrict__ d4,
                 const float* __restrict__ s5, bf16* __restrict__ d5,
                 const int* __restrict__ tok, const int* __restrict__ cat,
                 const float* __restrict__ wemb, const float* __restrict__ cemb,
                 bf16* __restrict__ X) {
    const int bid = blockIdx.x;
    if (bid < 10752) {
        const float* src; bf16* dst; int i8;
        if (bid < 3072) { src = s0; dst = d0; i8 = bid * 256 + threadIdx.x; }
        else {
            int r = (bid - 3072) / 1536;
            int rb = (bid - 3072) % 1536;
            i8 = rb * 256 + threadIdx.x;
            switch (r) {
                case 0: src = s1; dst = d1; break;
                case 1: src = s2; dst = d2; break;
                case 2: src = s3; dst = d3; break;
                case 3: src = s4; dst = d4; break;
                default: src = s5; dst = d5; break;
            }
        }
        const float4* s = (const float4*)(src + (size_t)i8 * 8);
        float4 a = s[0], b = s[1];
        ushort4 o0, o1;
        o0.x = __bfloat16_as_ushort(__float2bfloat16(a.x));
        o0.y = __bfloat16_as_ushort(__float2bfloat16(a.y));
        o0.z = __bfloat16_as_ushort(__float2bfloat16(a.z));
        o0.w = __bfloat16_as_ushort(__float2bfloat16(a.w));
        o1.x = __bfloat16_as_ushort(__float2bfloat16(b.x));
        o1.y = __bfloat16_as_ushort(__float2bfloat16(b.y));
        o1.z = __bfloat16_as_ushort(__float2bfloat16(b.z));
        o1.w = __bfloat16_as_ushort(__float2bfloat16(b.w));
        ((ushort4*)(dst + (size_t)i8 * 8))[0] = o0;
        ((ushort4*)(dst + (size_t)i8 * 8))[1] = o1;
    } else {
        const int tb = bid - 10752;
        const int t = tb >> 5, b = tb & 31;
        const int token = tok[b * T_ + t];
        const int c = cat[b * T_ + t];
        const int i = threadIdx.x;
        const float* src = (i < 128) ? (wemb + (size_t)token * H_ + (size_t)i * 8)
                                     : (cemb + (size_t)c * H_ + (size_t)(i - 128) * 8);
        float4 a = ((const float4*)src)[0];
        float4 bv = ((const float4*)src)[1];
        ushort4 o0, o1;
        o0.x = __bfloat16_as_ushort(__float2bfloat16(a.x));
        o0.y = __bfloat16_as_ushort(__float2bfloat16(a.y));
        o0.z = __bfloat16_as_ushort(__float2bfloat16(a.z));
        o0.w = __bfloat16_as_ushort(__float2bfloat16(a.w));
        o1.x = __bfloat16_as_ushort(__float2bfloat16(bv.x));
        o1.y = __bfloat16_as_ushort(__float2bfloat16(bv.y));
        o1.z = __bfloat16_as_ushort(__float2bfloat16(bv.z));
        o1.w = __bfloat16_as_ushort(__float2bfloat16(bv.w));
        ushort4* d = (ushort4*)(X + (size_t)tb * 2 * H_ + (size_t)i * 8);
        d[0] = o0;
        d[1] = o1;
    }
}

// ---------------------------------------------------------------------------
__global__ __launch_bounds__(256)
void gemm_bt(const bf16* __restrict__ A, const bf16* __restrict__ Bm,
             const float* __restrict__ bias, float* __restrict__ Cf,
             int M, int N, int K) {
    __shared__ __align__(16) bf16 As[128 * 64];
    __shared__ __align__(16) bf16 Bs[128 * 64];
    const int tid = threadIdx.x;
    const int lane = tid & 63;
    const int wid = tid >> 6;
    const int row0 = blockIdx.x * 128;
    const int col0 = blockIdx.y * 128;
    const int rw0 = (wid >> 1) * 64;
    const int cw0 = (wid & 1) * 64;
    const int lr = lane & 15;
    const int lg = lane >> 4;
    f32x4 acc[4][4] = {};
    const int nk = K >> 6;
    for (int kt = 0; kt < nk; ++kt) {
        const int k0 = kt * 64;
#pragma unroll
        for (int i = 0; i < 4; ++i) {
            int c = i * 256 + tid;
            int r = c >> 3;
            int kc = (c & 7) * 8;
            lds_cp16(A + (size_t)(row0 + r) * K + (k0 + kc), (void*)(As + c * 8));
            lds_cp16(Bm + (size_t)(col0 + r) * K + (k0 + kc), (void*)(Bs + c * 8));
        }
        __syncthreads();
#pragma unroll
        for (int s = 0; s < 2; ++s) {
            short8 af[4], bfr[4];
#pragma unroll
            for (int m = 0; m < 4; ++m)
                af[m] = *(const short8*)(As + (rw0 + m * 16 + lr) * 64 + s * 32 + lg * 8);
#pragma unroll
            for (int n = 0; n < 4; ++n)
                bfr[n] = *(const short8*)(Bs + (cw0 + n * 16 + lr) * 64 + s * 32 + lg * 8);
#pragma unroll
            for (int m = 0; m < 4; ++m)
#pragma unroll
                for (int n = 0; n < 4; ++n)
                    acc[m][n] = __builtin_amdgcn_mfma_f32_16x16x32_bf16(bfr[n], af[m], acc[m][n], 0, 0, 0);
        }
        __syncthreads();
    }
#pragma unroll
    for (int m = 0; m < 4; ++m) {
#pragma unroll
        for (int n = 0; n < 4; ++n) {
            int r = row0 + rw0 + m * 16 + lr;
            int c0b = col0 + cw0 + n * 16 + lg * 4;
            f32x4 v = acc[m][n] + *(const f32x4*)(bias + c0b);
            *(f32x4*)(Cf + (size_t)r * N + c0b) = v;
        }
    }
}

// ---------------------------------------------------------------------------
__global__ __launch_bounds__(256)
void stair_init(const float* __restrict__ h1, const float* __restrict__ h2,
                const float* __restrict__ h3, unsigned* __restrict__ Hx,
                int* __restrict__ flags, int* __restrict__ aux) {
    int idx = blockIdx.x * 256 + threadIdx.x;   // < 3*16384
    if (idx < NBS * FS) flags[idx] = 0;
    if (idx < 64 * FS + 64) aux[idx] = 0;
    int l = idx >> 14, r = idx & 16383;
    int b = r >> 9, k = r & 511;
    const float* h = (l == 0 ? h1 : (l == 1 ? h2 : h3));
    unsigned lo = __bfloat16_as_ushort(__float2bfloat16(h[b * H_ + 2 * k]));
    unsigned hi = __bfloat16_as_ushort(__float2bfloat16(h[b * H_ + 2 * k + 1]));
    Hx[((l * 2 + 0) * 32 + b) * 512 + k] = lo | (hi << 16);
}

// ---------------------------------------------------------------------------
__device__ __forceinline__ void wait_flags(const int* flags, int base, int nflags,
                                           int thr, int own) {
    const int tid = threadIdx.x;
    int mine = 1;
    const int* fp = nullptr;
    int idx = base + tid;
    if (tid < nflags) { fp = flags + (size_t)idx * FS; mine = (idx == own) ? 1 : 0; }
    int done = 0;
    do {
        if (!mine)
            mine = (__hip_atomic_load(fp, __ATOMIC_RELAXED, __HIP_MEMORY_SCOPE_AGENT) >= thr);
        done = __syncthreads_and(mine);
    } while (!done);
}

__device__ __forceinline__ void wait_flags_sleep(const int* flags, int base, int nflags,
                                                 int thr) {
    const int tid = threadIdx.x;
    int mine = 1;
    const int* fp = nullptr;
    if (tid < nflags) { fp = flags + (size_t)(base + tid) * FS; mine = 0; }
    int done = 0;
    do {
        if (!mine)
            mine = (__hip_atomic_load(fp, __ATOMIC_RELAXED, __HIP_MEMORY_SCOPE_AGENT) >= thr);
        done = __syncthreads_and(mine);
        if (!done) __builtin_amdgcn_s_sleep(16);
    } while (!done);
}

// ---------------------------------------------------------------------------
template<int BF16W>
__global__ __launch_bounds__(256, 1)
void stair_fc(const float* __restrict__ GI0,
              const bf16* __restrict__ Wih2, const bf16* __restrict__ Wih3,
              const bf16* __restrict__ Whh1, const bf16* __restrict__ Whh2,
              const bf16* __restrict__ Whh3,
              const float* __restrict__ bih2, const float* __restrict__ bih3,
              const float* __restrict__ bhh1, const float* __restrict__ bhh2,
              const float* __restrict__ bhh3,
              const float* __restrict__ h1, const float* __restrict__ h2,
              const float* __restrict__ h3,
              unsigned* __restrict__ Hx, int* __restrict__ flags,
              int* __restrict__ aux,
              unsigned* __restrict__ c1, unsigned* __restrict__ c2,
              unsigned* __restrict__ c3, float* __restrict__ outt,
              const float* __restrict__ fcw32, bf16* __restrict__ fcwB,
              const float* __restrict__ fcb, float* __restrict__ outp) {
    __shared__ __align__(16) char smem[127488];
    const int tid = threadIdx.x;
    const int lane = tid & 63;
    const int wid = tid >> 6;
    const int lr = lane & 15;
    const int lg = lane >> 4;

    if (blockIdx.x < NBS) {
        // ================= staircase path =================
        float* PlH = (float*)smem;
        float* PlI = (float*)(smem + 24576);
        float* RrH = (float*)(smem + 49152);
        float* RrI = (float*)(smem + 55296);
        char* cbuf = smem + 61440;                    // 32 rows x 2064B
        const int l = blockIdx.x >> 6;
        const int u0 = (blockIdx.x & 63) * 16;
        const int kbase = wid * 256;

        const bf16* Whh = (l == 0) ? Whh1 : ((l == 1) ? Whh2 : Whh3);
        const bf16* Wih = (l == 1) ? Wih2 : Wih3;
        const float* bhh = (l == 0) ? bhh1 : ((l == 1) ? bhh2 : bhh3);
        const float* bih = (l == 1) ? bih2 : bih3;
        const float* hinit = (l == 0) ? h1 : ((l == 1) ? h2 : h3);
        const unsigned short* wh = (const unsigned short*)Whh;
        const unsigned short* wi = (const unsigned short*)Wih;
        const unsigned* Cin = (l == 1) ? c1 : c2;
        unsigned* Cout = (l == 0) ? c1 : c2;

        short8 wfH[3][8];
#pragma unroll
        for (int g = 0; g < 3; ++g)
#pragma unroll
            for (int kf = 0; kf < 8; ++kf)
                wfH[g][kf] = *(const short8*)(wh + (size_t)(g * H_ + u0 + lr) * H_ + kbase + kf * 32 + lg * 8);

        const int gb = tid >> 3;
        const int up = tid & 7;
        float hold0 = hinit[(size_t)gb * H_ + u0 + 2 * up];
        float hold1 = hinit[(size_t)gb * H_ + u0 + 2 * up + 1];

        float bhA = bhh[((tid >> 3) >> 4) * H_ + u0 + ((tid >> 3) & 15)];
        float bhB = (tid < 128) ? bhh[(((tid + 256) >> 3) >> 4) * H_ + u0 + (((tid + 256) >> 3) & 15)] : 0.f;
        float biA = 0.f, biB = 0.f;
        if (l > 0) {
            biA = bih[((tid >> 3) >> 4) * H_ + u0 + ((tid >> 3) & 15)];
            if (tid < 128) biB = bih[(((tid + 256) >> 3) >> 4) * H_ + u0 + (((tid + 256) >> 3) & 15)];
        }

        for (int s = 0; s < NITER; ++s) {
            const int tl = s - 2 * l;
            const bool act = (tl >= 0) && (tl < T_);
            const int tln = tl + 1;
            const bool pre = (l > 0) && (tln >= 0) && (tln < T_);
            float g0r = 0.f, g0z = 0.f, g0n = 0.f, g1r = 0.f, g1z = 0.f, g1n = 0.f;
            if (l == 0 && act) {
                const float* gi = GI0 + ((size_t)tl * B_ + gb) * 3072 + u0 + 2 * up;
                g0r = gi[0];    g1r = gi[1];
                g0z = gi[1024]; g1z = gi[1025];
                g0n = gi[2048]; g1n = gi[2049];
            }
            // top-of-loop: own-layer RAW/WAR only (64 flags)
            wait_flags(flags, 64 * l, 64, s, blockIdx.x);

            f32x4 accH[2][3] = {};
            f32x4 accI[2][3] = {};
            f32x4 h4[16];
            if (act) {
                const char* hp0 = (const char*)(Hx + (size_t)((l * 2 + (tl & 1)) * 32 + lr) * 512);
                const char* hp1 = (const char*)(Hx + (size_t)((l * 2 + (tl & 1)) * 32 + 16 + lr) * 512);
#pragma unroll
                for (int kf = 0; kf < 8; ++kf) {
                    const int off = ((kbase >> 1) + kf * 16 + lg * 4) * 4;
                    h4[kf] = coh_ld16(hp0 + off);
                    h4[8 + kf] = coh_ld16(hp1 + off);
                }
                if (l > 0) {
#pragma unroll
                    for (int kf = 0; kf < 8; ++kf) {
                        const int kb2 = kbase * 2 + kf * 64 + lg * 16;
                        short8 cv0 = *(const short8*)(cbuf + lr * 2064 + kb2);
                        short8 cv1 = *(const short8*)(cbuf + (16 + lr) * 2064 + kb2);
                        const int ko = kbase + kf * 32 + lg * 8;
#pragma unroll
                        for (int g = 0; g < 3; ++g) {
                            short8 w = *(const short8*)(wi + (size_t)(g * H_ + u0 + lr) * H_ + ko);
                            accI[0][g] = __builtin_amdgcn_mfma_f32_16x16x32_bf16(cv0, w, accI[0][g], 0, 0, 0);
                            accI[1][g] = __builtin_amdgcn_mfma_f32_16x16x32_bf16(cv1, w, accI[1][g], 0, 0, 0);
                        }
                    }
                }
                wait_vm0();   // h4 ready
#pragma unroll
                for (int kf = 0; kf < 8; ++kf) {
                    v16 a0, a1;
                    a0.f = h4[kf];
                    a1.f = h4[8 + kf];
#pragma unroll
                    for (int g = 0; g < 3; ++g) {
                        accH[0][g] = __builtin_amdgcn_mfma_f32_16x16x32_bf16(a0.s, wfH[g][kf], accH[0][g], 0, 0, 0);
                        accH[1][g] = __builtin_amdgcn_mfma_f32_16x16x32_bf16(a1.s, wfH[g][kf], accH[1][g], 0, 0, 0);
                    }
                }
#pragma unroll
                for (int m = 0; m < 2; ++m)
#pragma unroll
                    for (int g = 0; g < 3; ++g) {
                        int col = g * 16 + lr;
                        int key = (col + (col >> 3)) & 7;
                        int byte_off = wid * 6144 + col * 128 + (((m * 16 + lg * 4) * 4) ^ (key << 4));
                        *(f32x4*)((char*)PlH + byte_off) = accH[m][g];
                        if (l > 0) *(f32x4*)((char*)PlI + byte_off) = accI[m][g];
                    }
            }
            __syncthreads();
            // l-1 wait only gates the prefetch (off the h-RAW path)
            f32x4 ct4[16];
            if (pre) {
                wait_flags(flags, 64 * (l - 1), 64, s, -1);
                const char* cp0 = (const char*)(Cin + (size_t)tln * (B_ * 512) + (size_t)lr * 512);
                const char* cp1 = (const char*)(Cin + (size_t)tln * (B_ * 512) + (size_t)(16 + lr) * 512);
#pragma unroll
                for (int kf = 0; kf < 8; ++kf) {
                    const int off = ((kbase >> 1) + kf * 16 + lg * 4) * 4;
                    ct4[kf] = coh_ld16(cp0 + off);
                    ct4[8 + kf] = coh_ld16(cp1 + off);
                }
            }
            if (act) {
#pragma unroll
                for (int it = 0; it < 2; ++it) {
                    int task = tid + it * 256;
                    if (task < 384) {
                        int col = task >> 3, bq = task & 7;
                        int key = (col + (col >> 3)) & 7;
                        int boff = col * 128 + ((bq * 16) ^ (key << 4));
                        float bh = (it == 0) ? bhA : bhB;
                        f32x4 s0 = *(const f32x4*)((const char*)PlH + boff);
                        f32x4 s1 = *(const f32x4*)((const char*)PlH + 6144 + boff);
                        f32x4 s2 = *(const f32x4*)((const char*)PlH + 12288 + boff);
                        f32x4 s3 = *(const f32x4*)((const char*)PlH + 18432 + boff);
                        f32x4 sv = (s0 + s1) + (s2 + s3);
                        sv[0] += bh; sv[1] += bh; sv[2] += bh; sv[3] += bh;
                        *(f32x4*)((char*)RrH + boff) = sv;
                        if (l > 0) {
                            float bi = (it == 0) ? biA : biB;
                            f32x4 t0 = *(const f32x4*)((const char*)PlI + boff);
                            f32x4 t1 = *(const f32x4*)((const char*)PlI + 6144 + boff);
                            f32x4 t2 = *(const f32x4*)((const char*)PlI + 12288 + boff);
                            f32x4 t3 = *(const f32x4*)((const char*)PlI + 18432 + boff);
                            f32x4 tv = (t0 + t1) + (t2 + t3);
                            tv[0] += bi; tv[1] += bi; tv[2] += bi; tv[3] += bi;
                            *(f32x4*)((char*)RrI + boff) = tv;
                        }
                    }
                }
            }
            __syncthreads();
            if (act) {
                float hn[2];
#pragma unroll
                for (int e = 0; e < 2; ++e) {
                    int u = 2 * up + e;
                    int colR = u, colZ = 16 + u, colN = 32 + u;
                    int keyR = (colR + (colR >> 3)) & 7;
                    int keyZ = (colZ + (colZ >> 3)) & 7;
                    int keyN = (colN + (colN >> 3)) & 7;
                    float ghr = *(const float*)((const char*)RrH + colR * 128 + ((gb * 4) ^ (keyR << 4)));
                    float ghz = *(const float*)((const char*)RrH + colZ * 128 + ((gb * 4) ^ (keyZ << 4)));
                    float ghn = *(const float*)((const char*)RrH + colN * 128 + ((gb * 4) ^ (keyN << 4)));
                    float gir, giz, gin;
                    if (l == 0) {
                        gir = (e == 0) ? g0r : g1r;
                        giz = (e == 0) ? g0z : g1z;
                        gin = (e == 0) ? g0n : g1n;
                    } else {
                        gir = *(const float*)((const char*)RrI + colR * 128 + ((gb * 4) ^ (keyR << 4)));
                        giz = *(const float*)((const char*)RrI + colZ * 128 + ((gb * 4) ^ (keyZ << 4)));
                        gin = *(const float*)((const char*)RrI + colN * 128 + ((gb * 4) ^ (keyN << 4)));
                    }
                    float holdv = (e == 0) ? hold0 : hold1;
                    float rr = 1.f / (1.f + expf(-(gir + ghr)));
                    float zz = 1.f / (1.f + expf(-(giz + ghz)));
                    float nn = tanhf(gin + rr * ghn);
                    float hnew = (1.f - zz) * nn + zz * holdv;
                    if (e == 0) hold0 = hnew; else hold1 = hnew;
                    hn[e] = hnew;
                }
                unsigned lo = __bfloat16_as_ushort(__float2bfloat16(hn[0]));
                unsigned hi = __bfloat16_as_ushort(__float2bfloat16(hn[1]));
                unsigned pk = lo | (hi << 16);
                coh_st4(Hx + (size_t)((l * 2 + ((tl + 1) & 1)) * 32 + gb) * 512 + (u0 >> 1) + up, pk);
                if (l < 2)
                    coh_st4(Cout + ((size_t)tl * B_ + gb) * 512 + (u0 >> 1) + up, pk);
                else
                    coh_st4(c3 + ((size_t)tl * B_ + gb) * 512 + (u0 >> 1) + up, pk);
            }
            wait_vm0();        // drain h/C stores + prefetch loads
            __syncthreads();
            if (tid == 0)
                coh_st4(&flags[(size_t)blockIdx.x * FS], (unsigned)(s + 1));
            if (pre) {
#pragma unroll
                for (int kf = 0; kf < 8; ++kf) {
                    const int kb2 = kbase * 2 + kf * 64 + lg * 16;
                    *(f32x4*)(cbuf + lr * 2064 + kb2) = ct4[kf];
                    *(f32x4*)(cbuf + (16 + lr) * 2064 + kb2) = ct4[8 + kf];
                }
            }
        }
        outt[(size_t)l * 32768 + (size_t)(tid >> 3) * H_ + u0 + 2 * (tid & 7)] = hold0;
        outt[(size_t)l * 32768 + (size_t)(tid >> 3) * H_ + u0 + 2 * (tid & 7) + 1] = hold1;
        __syncthreads();
        if (BF16W) wait_flags_sleep(aux + 64, 0, 64, 1);   // fcwB ready (long since)
    } else {
        // FC prologue: convert this block's 500-row fcw slice to bf16 (LLC stores)
        if (BF16W) {
            const int fcid = blockIdx.x - NBS;
            const float2* src = (const float2*)(fcw32 + (size_t)fcid * 500 * 1024);
            unsigned* dst = (unsigned*)fcwB + (size_t)fcid * 500 * 512;
            for (int i = tid; i < 500 * 512; i += 256) {
                float2 v = src[i];
                unsigned pk = (unsigned)__bfloat16_as_ushort(__float2bfloat16(v.x)) |
                              ((unsigned)__bfloat16_as_ushort(__float2bfloat16(v.y)) << 16);
                coh_st4(dst + i, pk);
            }
            wait_vm0();
            __syncthreads();
            if (tid == 0)
                coh_st4(&aux[64 + (blockIdx.x - NBS) * FS], 1u);
            wait_flags_sleep(aux + 64, 0, 64, 1);
        }
    }

    // ============== unified frontier-paced FC queue (all blocks) ==============
    {
        bf16* As = (bf16*)smem;
        bf16* Bs16 = (bf16*)(smem + 16384);
        float* Bs32 = (float*)(smem + 16384);
        int* jslot = (int*)(smem + 126976);
        const bf16* Abase = (const bf16*)c3;
        const bf16* fcwBr = (const bf16*)fcwB;
        const int rw0 = (wid >> 1) * 64;
        const int cw0 = (wid & 1) * 64;

        auto fc_tile = [&](int bx, int by) {
            const int row0 = bx * 128, col0 = by * 128;
            f32x4 acc[4][4] = {};
            for (int kt = 0; kt < 16; ++kt) {
                const int k0 = kt * 64;
#pragma unroll
                for (int i = 0; i < 4; ++i) {
                    int c = i * 256 + tid;
                    int r = c >> 3;
                    int sb = ((c & 7) * 16) ^ ((r & 7) << 4);
                    lds_cp16(Abase + (size_t)(row0 + r) * 1024 + k0 + (sb >> 1),
                             (char*)As + c * 16);
                }
                if (BF16W) {
#pragma unroll
                    for (int i = 0; i < 4; ++i) {
                        int c = i * 256 + tid;
                        int r = c >> 3;
                        int sb = ((c & 7) * 16) ^ ((r & 7) << 4);
                        lds_cp16(fcwBr + (size_t)(col0 + r) * 1024 + k0 + (sb >> 1),
                                 (char*)Bs16 + c * 16);
                    }
                } else {
#pragma unroll
                    for (int i = 0; i < 8; ++i) {
                        int c = i * 256 + tid;
                        int r = c >> 4;
                        int sb = ((c & 15) * 16) ^ ((r & 7) << 4);
                        lds_cp16(fcw32 + (size_t)(col0 + r) * 1024 + k0 + (sb >> 2),
                                 (char*)Bs32 + c * 16);
                    }
                }
                __syncthreads();
#pragma unroll
                for (int s = 0; s < 2; ++s) {
                    short8 af[4], bfr[4];
#pragma unroll
                    for (int m = 0; m < 4; ++m) {
                        int row = rw0 + m * 16 + lr;
                        int cb = (s * 64 + lg * 16) ^ ((row & 7) << 4);
                        af[m] = *(const short8*)((const char*)As + row * 128 + cb);
                    }
#pragma unroll
                    for (int n = 0; n < 4; ++n) {
                        int row = cw0 + n * 16 + lr;
                        if (BF16W) {
                            int cb = (s * 64 + lg * 16) ^ ((row & 7) << 4);
                            bfr[n] = *(const short8*)((const char*)Bs16 + row * 128 + cb);
                        } else {
                            int base = s * 128 + lg * 32;
                            int cb0 = base ^ ((row & 7) << 4);
                            int cb1 = (base + 16) ^ ((row & 7) << 4);
                            float4 fA = *(const float4*)((const char*)Bs32 + row * 256 + cb0);
                            float4 fB = *(const float4*)((const char*)Bs32 + row * 256 + cb1);
                            union { unsigned short us[8]; short8 s8; } t;
                            t.us[0] = __bfloat16_as_ushort(__float2bfloat16(fA.x));
                            t.us[1] = __bfloat16_as_ushort(__float2bfloat16(fA.y));
                            t.us[2] = __bfloat16_as_ushort(__float2bfloat16(fA.z));
                            t.us[3] = __bfloat16_as_ushort(__float2bfloat16(fA.w));
                            t.us[4] = __bfloat16_as_ushort(__float2bfloat16(fB.x));
                            t.us[5] = __bfloat16_as_ushort(__float2bfloat16(fB.y));
                            t.us[6] = __bfloat16_as_ushort(__float2bfloat16(fB.z));
                            t.us[7] = __bfloat16_as_ushort(__float2bfloat16(fB.w));
                            bfr[n] = t.s8;
                        }
                    }
#pragma unroll
                    for (int m = 0; m < 4; ++m)
#pragma unroll
                        for (int n = 0; n < 4; ++n)
                            acc[m][n] = __builtin_amdgcn_mfma_f32_16x16x32_bf16(bfr[n], af[m], acc[m][n], 0, 0, 0);
                }
                __syncthreads();
            }
#pragma unroll
            for (int m = 0; m < 4; ++m) {
#pragma unroll
                for (int n = 0; n < 4; ++n) {
                    int r = row0 + rw0 + m * 16 + lr;
                    int c0b = col0 + cw0 + n * 16 + lg * 4;
                    f32x4 v = acc[m][n] + *(const f32x4*)(fcb + c0b);
                    int b = r & 31, t = r >> 5;
                    nt_st16(outp + ((size_t)b * T_ + t) * (size_t)V_ + c0b, v);
                }
            }
        };

        // job j -> chunk = j/250 (bx0 = chunk*8), by = j%250; per-tile flag gate
        for (;;) {
            __syncthreads();
            if (tid == 0)
                *jslot = (int)__hip_atomic_fetch_add((unsigned*)aux, 1u,
                                                     __ATOMIC_RELAXED, __HIP_MEMORY_SCOPE_AGENT);
            __syncthreads();
            int job = *jslot;
            if (job >= NJOBS) break;
            int cidx = job / 250;
            int by = job - cidx * 250;
            int bx0 = cidx * 8;
            for (int e = 0; e < 8; ++e) {
                int bx = bx0 + e;
                wait_flags_sleep(flags, 2 * 64, 64, 4 * bx + 8);
                fc_tile(bx, by);
            }
        }
    }
}

// ---------------------------------------------------------------------------
extern "C" void kernel_launch(void* const* d_in, const int* in_sizes, int n_in,
                              void* d_out, int out_size, void* d_ws, size_t ws_size,
                              hipStream_t stream) {
    const int* tok = (const int*)d_in[0];
    const int* cat = (const int*)d_in[1];
    const float* h1 = (const float*)d_in[3];
    const float* h2 = (const float*)d_in[4];
    const float* h3 = (const float*)d_in[5];
    const float* wemb = (const float*)d_in[6];
    const float* cemb = (const float*)d_in[7];
    const float* Wih[3] = {(const float*)d_in[8], (const float*)d_in[12], (const float*)d_in[16]};
    const float* Whh[3] = {(const float*)d_in[9], (const float*)d_in[13], (const float*)d_in[17]};
    const float* bih[3] = {(const float*)d_in[10], (const float*)d_in[14], (const float*)d_in[18]};
    const float* bhh[3] = {(const float*)d_in[11], (const float*)d_in[15], (const float*)d_in[19]};
    const float* fcw = (const float*)d_in[20];
    const float* fcb = (const float*)d_in[21];
    float* out = (float*)d_out;

    char* ws = (char*)d_ws;
    unsigned* C3 = (unsigned*)ws;                       // 0 .. 8,388,608
    bf16* Xbf = (bf16*)(ws + 8388608);
    int* aux = (int*)(ws + 8388608);                    // overlays dead Xbf
    int* flags = (int*)(ws + 8388608) + 4096;
    bf16* WihB1 = (bf16*)(ws + 25165824);
    float* GI0 = (float*)(ws + 37748736);
    bf16* WihB2 = (bf16*)(ws + 88080384);
    bf16* WihB3 = (bf16*)(ws + 94371840);
    bf16* WhhB1 = (bf16*)(ws + 100663296);
    bf16* WhhB2 = (bf16*)(ws + 106954752);
    bf16* WhhB3 = (bf16*)(ws + 113246208);
    unsigned* Hx = (unsigned*)(ws + 119537664);
    unsigned* C1 = (unsigned*)(ws + 119931904);
    unsigned* C2 = (unsigned*)(ws + 128320512);
    bf16* fcwB = (bf16*)(ws + 136709120);               // .. 202,245,120
    const bool bigws = (ws_size >= 202245120ull);

    prep_kernel<<<14848, 256, 0, stream>>>(Wih[0], WihB1, Wih[1], WihB2, Wih[2], WihB3,
                                           Whh[0], WhhB1, Whh[1], WhhB2, Whh[2], WhhB3,
                                           tok, cat, wemb, cemb, Xbf);
    gemm_bt<<<dim3(32, 24), 256, 0, stream>>>(Xbf, WihB1, bih[0], GI0, 4096, 3072, 2048);
    stair_init<<<192, 256, 0, stream>>>(h1, h2, h3, Hx, flags, aux);
    float* out_tail = out + (size_t)B_ * T_ * V_;
    if (bigws)
        stair_fc<1><<<256, 256, 0, stream>>>(GI0, WihB2, WihB3, WhhB1, WhhB2, WhhB3,
                                             bih[1], bih[2], bhh[0], bhh[1], bhh[2],
                                             h1, h2, h3, Hx, flags, aux, C1, C2, C3, out_tail,
                                             fcw, fcwB, fcb, out);
    else
        stair_fc<0><<<256, 256, 0, stream>>>(GI0, WihB2, WihB3, WhhB1, WhhB2, WhhB3,
                                             bih[1], bih[2], bhh[0], bhh[1], bhh[2],
                                             h1, h2, h3, Hx, flags, aux, C1, C2, C3, out_tail,
                                             fcw, fcwB, fcb, out);
}